// Round 8
// baseline (811.350 us; speedup 1.0000x reference)
//
#include <hip/hip_runtime.h>
#include <math.h>

#define B_    16384
#define IN_   64
#define DENC_ 512
#define NE_   2048
#define P_    12
#define ROWS_ 196608      // B_*P_
#define BETA_ 0.25

// output layout (all float32, concatenated in return order)
#define XHAT_OFF 1
#define PERP_OFF 1048577   // 1 + 16384*64
#define IDXF_OFF 1048578
#define COEF_OFF 1245186   // IDXF_OFF + 196608

typedef __bf16 bf16x8 __attribute__((ext_vector_type(8)));
typedef float  f32x16 __attribute__((ext_vector_type(16)));

__device__ __forceinline__ void split3(float v, __bf16& h, __bf16& m, __bf16& l) {
    h = (__bf16)v;
    float r1 = v - (float)h;
    m = (__bf16)r1;
    float r2 = r1 - (float)m;
    l = (__bf16)r2;
}

// async global->LDS 16B per lane; dest = wave-uniform base + lane*16
__device__ __forceinline__ void gload_lds16(const void* g, void* l) {
    __builtin_amdgcn_global_load_lds((const __attribute__((address_space(1))) void*)g,
                                     (__attribute__((address_space(3))) void*)l, 16, 0, 0);
}

// ---------------------------------------------------------------------------
// Pre-split weights: W[K][N] f32 -> Wt planes [N][K] bf16 (hi/mid/lo).
// ---------------------------------------------------------------------------
__global__ void k_wsplit(const float* __restrict__ W,
                         __bf16* __restrict__ Wh, __bf16* __restrict__ Wm,
                         __bf16* __restrict__ Wl, int kshift, int N, int total) {
    int idx = blockIdx.x * 256 + threadIdx.x;
    if (idx < total) {
        int n = idx >> kshift;
        int k = idx & ((1 << kshift) - 1);
        float v = W[(size_t)k * N + n];
        __bf16 h, m, l;
        split3(v, h, m, l);
        Wh[idx] = h; Wm[idx] = m; Wl[idx] = l;
    }
}

// ---------------------------------------------------------------------------
// Activation split: A[row][K] f32 -> planes [row][K] bf16 (coalesced both
// sides; 8 elems/thread). Values identical to in-register split3.
// ---------------------------------------------------------------------------
__global__ __launch_bounds__(256) void k_asplit(const float* __restrict__ A,
                                                __bf16* __restrict__ Ah,
                                                __bf16* __restrict__ Am,
                                                __bf16* __restrict__ Al) {
    size_t i = ((size_t)blockIdx.x * 256 + threadIdx.x) * 8;
    float4 u0 = *(const float4*)(A + i);
    float4 u1 = *(const float4*)(A + i + 4);
    float v[8] = {u0.x, u0.y, u0.z, u0.w, u1.x, u1.y, u1.z, u1.w};
    bf16x8 ph, pm, pl;
#pragma unroll
    for (int j = 0; j < 8; ++j) {
        __bf16 hh, mm, ll;
        split3(v[j], hh, mm, ll);
        ph[j] = hh; pm[j] = mm; pl[j] = ll;
    }
    *(bf16x8*)(Ah + i) = ph;
    *(bf16x8*)(Am + i) = pm;
    *(bf16x8*)(Al + i) = pl;
}

// ---------------------------------------------------------------------------
// MFMA GEMM + bias, f32-A path (in-register split). Used for gemm1 (K=64).
// XCD-aware block swizzle. Bit-identical C vs baseline.
// ---------------------------------------------------------------------------
__global__ __launch_bounds__(256, 2) void k_gemm_mfma(const float* __restrict__ A,
                                                      const __bf16* __restrict__ Bh,
                                                      const __bf16* __restrict__ Bm,
                                                      const __bf16* __restrict__ Bl,
                                                      const float* __restrict__ bias,
                                                      float* __restrict__ C,
                                                      int N, int K) {
    __shared__ __bf16 eS[2][3][64 * 64];   // 48 KB

    const int nwg  = gridDim.x * gridDim.y;
    const int flat = blockIdx.y * gridDim.x + blockIdx.x;
    const int nf   = (flat & 7) * (nwg >> 3) + (flat >> 3);
    const int bx   = nf % gridDim.x;
    const int by   = nf / gridDim.x;

    const int tid = threadIdx.x;
    const int w = tid >> 6, lane = tid & 63;
    const int r0 = by * 256 + w * 64;
    const int n0 = bx * 64;
    const int lrow = lane & 31;
    const int half = lane >> 5;

    const int cc0 = tid >> 3, qq = tid & 7;
    const int cc1 = cc0 + 32;
    const size_t off0 = (size_t)cc0 * K + (size_t)((qq ^ (cc0 & 7)) * 8);
    const size_t off1 = (size_t)cc1 * K + (size_t)((qq ^ (cc1 & 7)) * 8);
    const size_t nbase = (size_t)n0 * K;
    const int ld0 = w * 512;
    const int ld1 = 2048 + w * 512;

    f32x16 acc00, acc01, acc10, acc11;
#pragma unroll
    for (int i = 0; i < 16; ++i) { acc00[i] = 0.0f; acc01[i] = 0.0f; acc10[i] = 0.0f; acc11[i] = 0.0f; }

    {
        const size_t b = nbase;
        gload_lds16(Bh + b + off0, &eS[0][0][ld0]);
        gload_lds16(Bh + b + off1, &eS[0][0][ld1]);
        gload_lds16(Bm + b + off0, &eS[0][1][ld0]);
        gload_lds16(Bm + b + off1, &eS[0][1][ld1]);
        gload_lds16(Bl + b + off0, &eS[0][2][ld0]);
        gload_lds16(Bl + b + off1, &eS[0][2][ld1]);
    }

    const int nch = K >> 6;
    for (int ch = 0; ch < nch; ++ch) {
        const int cur = ch & 1;
        __syncthreads();

        if (ch + 1 < nch) {
            const int nxt = cur ^ 1;
            const size_t b = nbase + (size_t)(ch + 1) * 64;
            gload_lds16(Bh + b + off0, &eS[nxt][0][ld0]);
            gload_lds16(Bh + b + off1, &eS[nxt][0][ld1]);
            gload_lds16(Bm + b + off0, &eS[nxt][1][ld0]);
            gload_lds16(Bm + b + off1, &eS[nxt][1][ld1]);
            gload_lds16(Bl + b + off0, &eS[nxt][2][ld0]);
            gload_lds16(Bl + b + off1, &eS[nxt][2][ld1]);
        }

        bf16x8 ah0[4], am0[4], al0[4], ah1[4], am1[4], al1[4];
        {
            const float* ar0 = A + (size_t)(r0 + lrow) * K + ch * 64 + half * 8;
            const float* ar1 = ar0 + (size_t)32 * K;
#pragma unroll
            for (int kc = 0; kc < 4; ++kc) {
                float4 u0 = *(const float4*)(ar0 + kc * 16);
                float4 u1 = *(const float4*)(ar0 + kc * 16 + 4);
                float va[8] = {u0.x, u0.y, u0.z, u0.w, u1.x, u1.y, u1.z, u1.w};
                float4 t0 = *(const float4*)(ar1 + kc * 16);
                float4 t1 = *(const float4*)(ar1 + kc * 16 + 4);
                float vb[8] = {t0.x, t0.y, t0.z, t0.w, t1.x, t1.y, t1.z, t1.w};
#pragma unroll
                for (int j = 0; j < 8; ++j) {
                    __bf16 hh, mm, ll;
                    split3(va[j], hh, mm, ll);
                    ah0[kc][j] = hh; am0[kc][j] = mm; al0[kc][j] = ll;
                    split3(vb[j], hh, mm, ll);
                    ah1[kc][j] = hh; am1[kc][j] = mm; al1[kc][j] = ll;
                }
            }
        }

#pragma unroll
        for (int kc = 0; kc < 4; ++kc) {
            const int q = kc * 2 + half;
            const int g = (q ^ (lrow & 7)) * 8;
            bf16x8 b0h = *(const bf16x8*)(&eS[cur][0][lrow * 64 + g]);
            bf16x8 b0m = *(const bf16x8*)(&eS[cur][1][lrow * 64 + g]);
            bf16x8 b0l = *(const bf16x8*)(&eS[cur][2][lrow * 64 + g]);
            bf16x8 b1h = *(const bf16x8*)(&eS[cur][0][(lrow + 32) * 64 + g]);
            bf16x8 b1m = *(const bf16x8*)(&eS[cur][1][(lrow + 32) * 64 + g]);
            bf16x8 b1l = *(const bf16x8*)(&eS[cur][2][(lrow + 32) * 64 + g]);

            acc00 = __builtin_amdgcn_mfma_f32_32x32x16_bf16(ah0[kc], b0h, acc00, 0, 0, 0);
            acc01 = __builtin_amdgcn_mfma_f32_32x32x16_bf16(ah0[kc], b1h, acc01, 0, 0, 0);
            acc10 = __builtin_amdgcn_mfma_f32_32x32x16_bf16(ah1[kc], b0h, acc10, 0, 0, 0);
            acc11 = __builtin_amdgcn_mfma_f32_32x32x16_bf16(ah1[kc], b1h, acc11, 0, 0, 0);
            acc00 = __builtin_amdgcn_mfma_f32_32x32x16_bf16(ah0[kc], b0m, acc00, 0, 0, 0);
            acc01 = __builtin_amdgcn_mfma_f32_32x32x16_bf16(ah0[kc], b1m, acc01, 0, 0, 0);
            acc10 = __builtin_amdgcn_mfma_f32_32x32x16_bf16(ah1[kc], b0m, acc10, 0, 0, 0);
            acc11 = __builtin_amdgcn_mfma_f32_32x32x16_bf16(ah1[kc], b1m, acc11, 0, 0, 0);
            acc00 = __builtin_amdgcn_mfma_f32_32x32x16_bf16(am0[kc], b0h, acc00, 0, 0, 0);
            acc01 = __builtin_amdgcn_mfma_f32_32x32x16_bf16(am0[kc], b1h, acc01, 0, 0, 0);
            acc10 = __builtin_amdgcn_mfma_f32_32x32x16_bf16(am1[kc], b0h, acc10, 0, 0, 0);
            acc11 = __builtin_amdgcn_mfma_f32_32x32x16_bf16(am1[kc], b1h, acc11, 0, 0, 0);
            acc00 = __builtin_amdgcn_mfma_f32_32x32x16_bf16(ah0[kc], b0l, acc00, 0, 0, 0);
            acc01 = __builtin_amdgcn_mfma_f32_32x32x16_bf16(ah0[kc], b1l, acc01, 0, 0, 0);
            acc10 = __builtin_amdgcn_mfma_f32_32x32x16_bf16(ah1[kc], b0l, acc10, 0, 0, 0);
            acc11 = __builtin_amdgcn_mfma_f32_32x32x16_bf16(ah1[kc], b1l, acc11, 0, 0, 0);
            acc00 = __builtin_amdgcn_mfma_f32_32x32x16_bf16(am0[kc], b0m, acc00, 0, 0, 0);
            acc01 = __builtin_amdgcn_mfma_f32_32x32x16_bf16(am0[kc], b1m, acc01, 0, 0, 0);
            acc10 = __builtin_amdgcn_mfma_f32_32x32x16_bf16(am1[kc], b0m, acc10, 0, 0, 0);
            acc11 = __builtin_amdgcn_mfma_f32_32x32x16_bf16(am1[kc], b1m, acc11, 0, 0, 0);
            acc00 = __builtin_amdgcn_mfma_f32_32x32x16_bf16(al0[kc], b0h, acc00, 0, 0, 0);
            acc01 = __builtin_amdgcn_mfma_f32_32x32x16_bf16(al0[kc], b1h, acc01, 0, 0, 0);
            acc10 = __builtin_amdgcn_mfma_f32_32x32x16_bf16(al1[kc], b0h, acc10, 0, 0, 0);
            acc11 = __builtin_amdgcn_mfma_f32_32x32x16_bf16(al1[kc], b1h, acc11, 0, 0, 0);
        }
    }

    const int col0 = n0 + lrow, col1 = col0 + 32;
    const float bv0 = bias[col0], bv1 = bias[col1];
#pragma unroll
    for (int r = 0; r < 16; ++r) {
        int rr = (r & 3) + 8 * (r >> 2) + 4 * half;
        C[(size_t)(r0 + rr) * N + col0] = acc00[r] + bv0;
        C[(size_t)(r0 + rr) * N + col1] = acc01[r] + bv1;
        C[(size_t)(r0 + 32 + rr) * N + col0] = acc10[r] + bv0;
        C[(size_t)(r0 + 32 + rr) * N + col1] = acc11[r] + bv1;
    }
}

// ---------------------------------------------------------------------------
// MFMA GEMM + bias, pre-split-A path: A as bf16 planes [row][K]. No split
// VALU in the loop. Same MFMA term order -> bit-identical C. XCD swizzle.
// ---------------------------------------------------------------------------
__global__ __launch_bounds__(256, 2) void k_gemm_mfma_p(const __bf16* __restrict__ Ah,
                                                        const __bf16* __restrict__ Am,
                                                        const __bf16* __restrict__ Al,
                                                        const __bf16* __restrict__ Bh,
                                                        const __bf16* __restrict__ Bm,
                                                        const __bf16* __restrict__ Bl,
                                                        const float* __restrict__ bias,
                                                        float* __restrict__ C,
                                                        int N, int K) {
    __shared__ __bf16 eS[2][3][64 * 64];   // 48 KB

    const int nwg  = gridDim.x * gridDim.y;
    const int flat = blockIdx.y * gridDim.x + blockIdx.x;
    const int nf   = (flat & 7) * (nwg >> 3) + (flat >> 3);
    const int bx   = nf % gridDim.x;
    const int by   = nf / gridDim.x;

    const int tid = threadIdx.x;
    const int w = tid >> 6, lane = tid & 63;
    const int r0 = by * 256 + w * 64;
    const int n0 = bx * 64;
    const int lrow = lane & 31;
    const int half = lane >> 5;

    const int cc0 = tid >> 3, qq = tid & 7;
    const int cc1 = cc0 + 32;
    const size_t off0 = (size_t)cc0 * K + (size_t)((qq ^ (cc0 & 7)) * 8);
    const size_t off1 = (size_t)cc1 * K + (size_t)((qq ^ (cc1 & 7)) * 8);
    const size_t nbase = (size_t)n0 * K;
    const int ld0 = w * 512;
    const int ld1 = 2048 + w * 512;

    f32x16 acc00, acc01, acc10, acc11;
#pragma unroll
    for (int i = 0; i < 16; ++i) { acc00[i] = 0.0f; acc01[i] = 0.0f; acc10[i] = 0.0f; acc11[i] = 0.0f; }

    {
        const size_t b = nbase;
        gload_lds16(Bh + b + off0, &eS[0][0][ld0]);
        gload_lds16(Bh + b + off1, &eS[0][0][ld1]);
        gload_lds16(Bm + b + off0, &eS[0][1][ld0]);
        gload_lds16(Bm + b + off1, &eS[0][1][ld1]);
        gload_lds16(Bl + b + off0, &eS[0][2][ld0]);
        gload_lds16(Bl + b + off1, &eS[0][2][ld1]);
    }

    const int nch = K >> 6;
    for (int ch = 0; ch < nch; ++ch) {
        const int cur = ch & 1;
        __syncthreads();

        if (ch + 1 < nch) {
            const int nxt = cur ^ 1;
            const size_t b = nbase + (size_t)(ch + 1) * 64;
            gload_lds16(Bh + b + off0, &eS[nxt][0][ld0]);
            gload_lds16(Bh + b + off1, &eS[nxt][0][ld1]);
            gload_lds16(Bm + b + off0, &eS[nxt][1][ld0]);
            gload_lds16(Bm + b + off1, &eS[nxt][1][ld1]);
            gload_lds16(Bl + b + off0, &eS[nxt][2][ld0]);
            gload_lds16(Bl + b + off1, &eS[nxt][2][ld1]);
        }

        // A fragments: direct 16B plane loads (no split VALU)
        bf16x8 ah0[4], am0[4], al0[4], ah1[4], am1[4], al1[4];
        {
            const size_t base0 = (size_t)(r0 + lrow) * K + ch * 64 + half * 8;
            const size_t base1 = base0 + (size_t)32 * K;
#pragma unroll
            for (int kc = 0; kc < 4; ++kc) {
                ah0[kc] = *(const bf16x8*)(Ah + base0 + kc * 16);
                am0[kc] = *(const bf16x8*)(Am + base0 + kc * 16);
                al0[kc] = *(const bf16x8*)(Al + base0 + kc * 16);
                ah1[kc] = *(const bf16x8*)(Ah + base1 + kc * 16);
                am1[kc] = *(const bf16x8*)(Am + base1 + kc * 16);
                al1[kc] = *(const bf16x8*)(Al + base1 + kc * 16);
            }
        }

#pragma unroll
        for (int kc = 0; kc < 4; ++kc) {
            const int q = kc * 2 + half;
            const int g = (q ^ (lrow & 7)) * 8;
            bf16x8 b0h = *(const bf16x8*)(&eS[cur][0][lrow * 64 + g]);
            bf16x8 b0m = *(const bf16x8*)(&eS[cur][1][lrow * 64 + g]);
            bf16x8 b0l = *(const bf16x8*)(&eS[cur][2][lrow * 64 + g]);
            bf16x8 b1h = *(const bf16x8*)(&eS[cur][0][(lrow + 32) * 64 + g]);
            bf16x8 b1m = *(const bf16x8*)(&eS[cur][1][(lrow + 32) * 64 + g]);
            bf16x8 b1l = *(const bf16x8*)(&eS[cur][2][(lrow + 32) * 64 + g]);

            acc00 = __builtin_amdgcn_mfma_f32_32x32x16_bf16(ah0[kc], b0h, acc00, 0, 0, 0);
            acc01 = __builtin_amdgcn_mfma_f32_32x32x16_bf16(ah0[kc], b1h, acc01, 0, 0, 0);
            acc10 = __builtin_amdgcn_mfma_f32_32x32x16_bf16(ah1[kc], b0h, acc10, 0, 0, 0);
            acc11 = __builtin_amdgcn_mfma_f32_32x32x16_bf16(ah1[kc], b1h, acc11, 0, 0, 0);
            acc00 = __builtin_amdgcn_mfma_f32_32x32x16_bf16(ah0[kc], b0m, acc00, 0, 0, 0);
            acc01 = __builtin_amdgcn_mfma_f32_32x32x16_bf16(ah0[kc], b1m, acc01, 0, 0, 0);
            acc10 = __builtin_amdgcn_mfma_f32_32x32x16_bf16(ah1[kc], b0m, acc10, 0, 0, 0);
            acc11 = __builtin_amdgcn_mfma_f32_32x32x16_bf16(ah1[kc], b1m, acc11, 0, 0, 0);
            acc00 = __builtin_amdgcn_mfma_f32_32x32x16_bf16(am0[kc], b0h, acc00, 0, 0, 0);
            acc01 = __builtin_amdgcn_mfma_f32_32x32x16_bf16(am0[kc], b1h, acc01, 0, 0, 0);
            acc10 = __builtin_amdgcn_mfma_f32_32x32x16_bf16(am1[kc], b0h, acc10, 0, 0, 0);
            acc11 = __builtin_amdgcn_mfma_f32_32x32x16_bf16(am1[kc], b1h, acc11, 0, 0, 0);
            acc00 = __builtin_amdgcn_mfma_f32_32x32x16_bf16(ah0[kc], b0l, acc00, 0, 0, 0);
            acc01 = __builtin_amdgcn_mfma_f32_32x32x16_bf16(ah0[kc], b1l, acc01, 0, 0, 0);
            acc10 = __builtin_amdgcn_mfma_f32_32x32x16_bf16(ah1[kc], b0l, acc10, 0, 0, 0);
            acc11 = __builtin_amdgcn_mfma_f32_32x32x16_bf16(ah1[kc], b1l, acc11, 0, 0, 0);
            acc00 = __builtin_amdgcn_mfma_f32_32x32x16_bf16(am0[kc], b0m, acc00, 0, 0, 0);
            acc01 = __builtin_amdgcn_mfma_f32_32x32x16_bf16(am0[kc], b1m, acc01, 0, 0, 0);
            acc10 = __builtin_amdgcn_mfma_f32_32x32x16_bf16(am1[kc], b0m, acc10, 0, 0, 0);
            acc11 = __builtin_amdgcn_mfma_f32_32x32x16_bf16(am1[kc], b1m, acc11, 0, 0, 0);
            acc00 = __builtin_amdgcn_mfma_f32_32x32x16_bf16(al0[kc], b0h, acc00, 0, 0, 0);
            acc01 = __builtin_amdgcn_mfma_f32_32x32x16_bf16(al0[kc], b1h, acc01, 0, 0, 0);
            acc10 = __builtin_amdgcn_mfma_f32_32x32x16_bf16(al1[kc], b0h, acc10, 0, 0, 0);
            acc11 = __builtin_amdgcn_mfma_f32_32x32x16_bf16(al1[kc], b1h, acc11, 0, 0, 0);
        }
    }

    const int col0 = n0 + lrow, col1 = col0 + 32;
    const float bv0 = bias[col0], bv1 = bias[col1];
#pragma unroll
    for (int r = 0; r < 16; ++r) {
        int rr = (r & 3) + 8 * (r >> 2) + 4 * half;
        C[(size_t)(r0 + rr) * N + col0] = acc00[r] + bv0;
        C[(size_t)(r0 + rr) * N + col1] = acc01[r] + bv1;
        C[(size_t)(r0 + 32 + rr) * N + col0] = acc10[r] + bv0;
        C[(size_t)(r0 + 32 + rr) * N + col1] = acc11[r] + bv1;
    }
}

// ---------------------------------------------------------------------------
// h = h + relu(layer_norm(t) * g + beta)
// ---------------------------------------------------------------------------
__global__ __launch_bounds__(256) void k_lnrelu(const float* __restrict__ t,
                                                float* __restrict__ h,
                                                const float* __restrict__ g,
                                                const float* __restrict__ beta) {
    const int tid = threadIdx.x;
    const int wv = tid >> 6, lane = tid & 63;
    const int row = blockIdx.x * 4 + wv;
    const float* tr = t + (size_t)row * DENC_;
    float* hr = h + (size_t)row * DENC_;

    float4 v0 = *(const float4*)(tr + lane * 4);
    float4 v1 = *(const float4*)(tr + 256 + lane * 4);

    float s = v0.x + v0.y + v0.z + v0.w + v1.x + v1.y + v1.z + v1.w;
#pragma unroll
    for (int m = 1; m < 64; m <<= 1) s += __shfl_xor(s, m);
    float mu = s / 512.0f;

    float d0x = v0.x - mu, d0y = v0.y - mu, d0z = v0.z - mu, d0w = v0.w - mu;
    float d1x = v1.x - mu, d1y = v1.y - mu, d1z = v1.z - mu, d1w = v1.w - mu;
    float vs = d0x * d0x + d0y * d0y + d0z * d0z + d0w * d0w +
               d1x * d1x + d1y * d1y + d1z * d1z + d1w * d1w;
#pragma unroll
    for (int m = 1; m < 64; m <<= 1) vs += __shfl_xor(vs, m);
    float var = vs / 512.0f;
    float rs = (float)(1.0 / sqrt((double)var + 1e-5));

    float4 g0 = *(const float4*)(g + lane * 4);
    float4 g1 = *(const float4*)(g + 256 + lane * 4);
    float4 b0 = *(const float4*)(beta + lane * 4);
    float4 b1 = *(const float4*)(beta + 256 + lane * 4);

    float4 h0 = *(float4*)(hr + lane * 4);
    float4 h1 = *(float4*)(hr + 256 + lane * 4);

    h0.x += fmaxf(d0x * rs * g0.x + b0.x, 0.0f);
    h0.y += fmaxf(d0y * rs * g0.y + b0.y, 0.0f);
    h0.z += fmaxf(d0z * rs * g0.z + b0.z, 0.0f);
    h0.w += fmaxf(d0w * rs * g0.w + b0.w, 0.0f);
    h1.x += fmaxf(d1x * rs * g1.x + b1.x, 0.0f);
    h1.y += fmaxf(d1y * rs * g1.y + b1.y, 0.0f);
    h1.z += fmaxf(d1z * rs * g1.z + b1.z, 0.0f);
    h1.w += fmaxf(d1w * rs * g1.w + b1.w, 0.0f);

    *(float4*)(hr + lane * 4) = h0;
    *(float4*)(hr + 256 + lane * 4) = h1;
}

// ---------------------------------------------------------------------------
// Codebook split (coalesced) + se
// ---------------------------------------------------------------------------
__global__ __launch_bounds__(256) void k_esplit_fast(const float* __restrict__ emb,
                                                     __bf16* __restrict__ Ehi,
                                                     __bf16* __restrict__ Emid,
                                                     __bf16* __restrict__ Elo) {
    const int wv = threadIdx.x >> 6, lane = threadIdx.x & 63;
    const int c = blockIdx.x * 4 + wv;
    float v = emb[(size_t)c * 64 + lane];
    __bf16 h, m, l;
    split3(v, h, m, l);
    Ehi[(size_t)c * 64 + lane] = h;
    Emid[(size_t)c * 64 + lane] = m;
    Elo[(size_t)c * 64 + lane] = l;
}

__global__ void k_esq(const float* __restrict__ emb, float* __restrict__ se) {
    int t = blockIdx.x * 256 + threadIdx.x;
    if (t < NE_) {
        float s = 0.0f;
        for (int k = 0; k < 64; ++k) {
            float v = emb[(size_t)t * 64 + k];
            s += v * v;
        }
        se[t] = s;
    }
}

// ---------------------------------------------------------------------------
// sz[row] = sum(z[row]^2)
// ---------------------------------------------------------------------------
__global__ __launch_bounds__(256) void k_rowsq(const float* __restrict__ z,
                                               float* __restrict__ sz) {
    const int tid = threadIdx.x;
    const int row = blockIdx.x * 64 + (tid >> 2);
    const int part = tid & 3;
    const float4* zp = (const float4*)(z + (size_t)row * 64) + part * 4;
    float s = 0.0f;
#pragma unroll
    for (int i = 0; i < 4; ++i) {
        float4 v = zp[i];
        s += v.x * v.x + v.y * v.y + v.z * v.z + v.w * v.w;
    }
    s += __shfl_xor(s, 1);
    s += __shfl_xor(s, 2);
    if (part == 0) sz[row] = s;
}

// ---------------------------------------------------------------------------
// MFMA distance + argmin: R7 structure (24KB LDS, 32-col chunks), with
// TRANSPOSED [granule][col] LDS plane layout: read bank = (lrow*4+w)%32 ->
// zero extra bank conflicts (was 4-way: col stride 128B made bank depend
// on granule only). Pure index permutation -> same values in same registers
// -> bit-identical d/idx.
// ---------------------------------------------------------------------------
__global__ __launch_bounds__(256) void k_distm(const float* __restrict__ z,
                                               const float* __restrict__ se,
                                               const float* __restrict__ sz,
                                               const __bf16* __restrict__ Ehi,
                                               const __bf16* __restrict__ Emid,
                                               const __bf16* __restrict__ Elo,
                                               int* __restrict__ idxw,
                                               float* __restrict__ idxf,
                                               float* __restrict__ lossacc,
                                               int* __restrict__ counts) {
    __shared__ __bf16 eS[2][3][32 * 64];   // 24 KB; plane layout [q(8)][col(32)]x8

    const int tid = threadIdx.x;
    const int w = tid >> 6, lane = tid & 63;
    const int r0 = blockIdx.x * 128 + w * 32;
    const int lrow = lane & 31;
    const int half = lane >> 5;

    // staging: lane writes LDS elems (w*512 + l*8): q = 2w + (l>>5), col = l&31
    // source elem = col*64 + q*8 within the chunk
    const int off = (tid & 31) * 64 + ((tid >> 5) & 1) * 8 + (tid >> 6) * 16;
    const int ld = w * 512;

    // persistent A fragments (3-way split of z rows)
    bf16x8 ah[4], am[4], al[4];
    {
        const float* zr = z + (size_t)(r0 + lrow) * 64 + half * 8;
#pragma unroll
        for (int kc = 0; kc < 4; ++kc) {
            float4 u0 = *(const float4*)(zr + kc * 16);
            float4 u1 = *(const float4*)(zr + kc * 16 + 4);
            float v[8] = {u0.x, u0.y, u0.z, u0.w, u1.x, u1.y, u1.z, u1.w};
#pragma unroll
            for (int j = 0; j < 8; ++j) {
                __bf16 hh, mm, ll;
                split3(v[j], hh, mm, ll);
                ah[kc][j] = hh; am[kc][j] = mm; al[kc][j] = ll;
            }
        }
    }

    float szv[16];
#pragma unroll
    for (int r = 0; r < 16; ++r) {
        int rl = (r & 3) + 8 * (r >> 2) + 4 * half;
        szv[r] = sz[r0 + rl];
    }

    float bd[16];
    int bi[16];
#pragma unroll
    for (int r = 0; r < 16; ++r) { bd[r] = 1e30f; bi[r] = 0; }

    // prologue: stage chunk 0 into buffer 0
    gload_lds16(Ehi + off, &eS[0][0][ld]);
    gload_lds16(Emid + off, &eS[0][1][ld]);
    gload_lds16(Elo + off, &eS[0][2][ld]);

    for (int ch = 0; ch < 64; ++ch) {
        const int cur = ch & 1;
        __syncthreads();   // drains stage(ch); issued a full compute phase ago

        if (ch + 1 < 64) {
            const int nxt = cur ^ 1;
            const int b = (ch + 1) * 2048;
            gload_lds16(Ehi + b + off, &eS[nxt][0][ld]);
            gload_lds16(Emid + b + off, &eS[nxt][1][ld]);
            gload_lds16(Elo + b + off, &eS[nxt][2][ld]);
        }

        f32x16 acc;
#pragma unroll
        for (int i = 0; i < 16; ++i) acc[i] = 0.0f;

#pragma unroll
        for (int kc = 0; kc < 4; ++kc) {
            const int q = kc * 2 + half;
            const int e = q * 256 + lrow * 8;
            bf16x8 bh = *(const bf16x8*)(&eS[cur][0][e]);
            bf16x8 bm = *(const bf16x8*)(&eS[cur][1][e]);
            bf16x8 bl = *(const bf16x8*)(&eS[cur][2][e]);

            acc = __builtin_amdgcn_mfma_f32_32x32x16_bf16(ah[kc], bh, acc, 0, 0, 0);
            acc = __builtin_amdgcn_mfma_f32_32x32x16_bf16(ah[kc], bm, acc, 0, 0, 0);
            acc = __builtin_amdgcn_mfma_f32_32x32x16_bf16(am[kc], bh, acc, 0, 0, 0);
            acc = __builtin_amdgcn_mfma_f32_32x32x16_bf16(ah[kc], bl, acc, 0, 0, 0);
            acc = __builtin_amdgcn_mfma_f32_32x32x16_bf16(am[kc], bm, acc, 0, 0, 0);
            acc = __builtin_amdgcn_mfma_f32_32x32x16_bf16(al[kc], bh, acc, 0, 0, 0);
        }

        const int c0 = ch * 32;
        const float se0 = se[c0 + lrow];
        const int   ci0 = c0 + lrow;
#pragma unroll
        for (int r = 0; r < 16; ++r) {
            float d0 = fmaf(-2.0f, acc[r], szv[r] + se0);
            if (d0 < bd[r]) { bd[r] = d0; bi[r] = ci0; }
        }
    }

    // cross-lane argmin within each 32-lane half (lexicographic: d, then idx)
#pragma unroll
    for (int r = 0; r < 16; ++r) {
        float d = bd[r];
        int i = bi[r];
#pragma unroll
        for (int off2 = 1; off2 < 32; off2 <<= 1) {
            float od = __shfl_xor(d, off2);
            int oi = __shfl_xor(i, off2);
            if (od < d || (od == d && oi < i)) { d = od; i = oi; }
        }
        bd[r] = d; bi[r] = i;
    }

    if (lrow == 0) {
        float lsum = 0.0f;
#pragma unroll
        for (int r = 0; r < 16; ++r) {
            int rl = (r & 3) + 8 * (r >> 2) + 4 * half;
            int row = r0 + rl;
            idxw[row] = bi[r];
            idxf[row] = (float)bi[r];
            lsum += bd[r];
            atomicAdd(&counts[bi[r]], 1);
        }
        atomicAdd(lossacc, lsum);
    }
}

// ---------------------------------------------------------------------------
// loss (from accumulated dmin sum) + perplexity (from counts)
// ---------------------------------------------------------------------------
__global__ __launch_bounds__(256) void k_lossperp(const float* __restrict__ lossacc,
                                                  const int* __restrict__ counts,
                                                  float* __restrict__ out) {
    __shared__ double red[256];
    const int tid = threadIdx.x;

    double hsum = 0.0;
    for (int i = tid; i < NE_; i += 256) {
        float p = (float)counts[i] / 196608.0f;
        float lg = logf(p + 1e-10f);
        hsum += (double)(p * lg);
    }
    red[tid] = hsum;
    __syncthreads();
    for (int off = 128; off > 0; off >>= 1) {
        if (tid < off) red[tid] += red[tid + off];
        __syncthreads();
    }
    if (tid == 0) {
        out[PERP_OFF] = (float)exp(-red[0]);
        out[0] = (float)((double)lossacc[0] * (1.0 + BETA_) / ((double)ROWS_ * IN_));
    }
}

// ---------------------------------------------------------------------------
// per-block pinv least-squares (single-wave workgroup)
// ---------------------------------------------------------------------------
__global__ __launch_bounds__(64) void k_pinv(const float* __restrict__ xin,
                                             const float* __restrict__ emb,
                                             const int* __restrict__ idxw,
                                             float* __restrict__ coeff,
                                             float* __restrict__ xhat) {
    __shared__ float aS[12][65];
    __shared__ float xS[64];
    __shared__ double GS[12][12];
    __shared__ double bS[12];
    __shared__ double yS[12];
    __shared__ double uS[12];
    __shared__ float cS[12];

    const int lane = threadIdx.x;
    const int b = blockIdx.x;

    int my = 0;
    if (lane < 12) my = idxw[(size_t)b * 12 + lane];
    int id[12];
#pragma unroll
    for (int p = 0; p < 12; ++p) id[p] = __shfl(my, p);

    int rep = lane, mcnt = 1;
    if (lane < 12) {
        rep = -1;
        mcnt = 0;
        for (int q = 0; q < 12; ++q) {
            if (id[q] == id[lane]) {
                if (rep < 0) rep = q;
                mcnt++;
            }
        }
    }

#pragma unroll
    for (int p = 0; p < 12; ++p) aS[p][lane] = emb[(size_t)id[p] * 64 + lane];
    xS[lane] = xin[(size_t)b * 64 + lane];
    __syncthreads();

    for (int item = lane; item < 90; item += 64) {
        if (item < 78) {
            int j = 0, k = 0, c = item;
            for (j = 0; j < 12; ++j) {
                int cnt = 12 - j;
                if (c < cnt) { k = j + c; break; }
                c -= cnt;
            }
            double s = 0.0;
            for (int t = 0; t < 64; ++t) s += (double)aS[j][t] * (double)aS[k][t];
            GS[j][k] = s;
            GS[k][j] = s;
        } else {
            int j = item - 78;
            double s = 0.0;
            for (int t = 0; t < 64; ++t) s += (double)aS[j][t] * (double)xS[t];
            bS[j] = s;
        }
    }
    __syncthreads();

    if (lane == 0) {
        for (int p = 0; p < 12; ++p) {
            int rp = -1;
            for (int q = 0; q < 12; ++q) {
                if (id[q] == id[p]) { rp = q; break; }
            }
            if (rp != p) {
                for (int q = 0; q < 12; ++q) {
                    GS[p][q] = 0.0;
                    GS[q][p] = 0.0;
                }
                GS[p][p] = 1.0;
                bS[p] = 0.0;
            }
        }
    }
    __syncthreads();

    for (int j = 0; j < 12; ++j) {
        if (lane == j) {
            double s = GS[j][j];
            for (int k = 0; k < j; ++k) {
                double l = GS[j][k];
                s -= l * l;
            }
            GS[j][j] = sqrt(fmax(s, 1e-30));
        }
        __syncthreads();
        if (lane > j && lane < 12) {
            double s = GS[lane][j];
            for (int k = 0; k < j; ++k) s -= GS[lane][k] * GS[j][k];
            GS[lane][j] = s / GS[j][j];
        }
        __syncthreads();
    }

    double s = (lane < 12) ? bS[lane] : 0.0;
    for (int k = 0; k < 12; ++k) {
        if (lane == k) yS[k] = s / GS[k][k];
        __syncthreads();
        double yk = yS[k];
        if (lane > k && lane < 12) s -= GS[lane][k] * yk;
    }
    double tacc = 0.0;
    for (int k = 11; k >= 0; --k) {
        if (lane == k) uS[k] = (yS[k] - tacc) / GS[k][k];
        __syncthreads();
        double uk = uS[k];
        if (lane < k) tacc += GS[k][lane] * uk;
    }
    __syncthreads();

    if (lane < 12) {
        double c = uS[rep] / (double)mcnt;
        coeff[(size_t)b * 12 + lane] = (float)c;
        cS[lane] = (float)c;
    }
    __syncthreads();

    float sx = 0.0f;
#pragma unroll
    for (int p = 0; p < 12; ++p) sx += aS[p][lane] * cS[p];
    xhat[(size_t)b * 64 + lane] = sx;
}

// ---------------------------------------------------------------------------

extern "C" void kernel_launch(void* const* d_in, const int* in_sizes, int n_in,
                              void* d_out, int out_size, void* d_ws, size_t ws_size,
                              hipStream_t stream) {
    const float* x        = (const float*)d_in[0];
    const float* enc_w1   = (const float*)d_in[1];
    const float* enc_b1   = (const float*)d_in[2];
    const float* res_w    = (const float*)d_in[3];
    const float* res_b    = (const float*)d_in[4];
    const float* res_g    = (const float*)d_in[5];
    const float* res_beta = (const float*)d_in[6];
    const float* enc_w2   = (const float*)d_in[7];
    const float* enc_b2   = (const float*)d_in[8];
    const float* emb      = (const float*)d_in[9];

    float* out = (float*)d_out;

    // workspace layout
    float* h  = (float*)d_ws;            // B*512 f32 (32MB), reused after enc2
    float* tz = h + (size_t)B_ * DENC_;  // B*768 f32 (48MB): t then z
    // VQ scratch overlapping h (dead after enc2):
    float* se    = h;                                        // 2048
    float* sz    = h + 2048;                                 // ROWS_
    int*   idxw  = (int*)(h + 2048 + (size_t)ROWS_);         // ROWS_
    int*   cnts  = (int*)(h + 2048 + 2 * (size_t)ROWS_);     // 2048
    float* lossacc = (float*)(cnts + NE_);                   // 1 (+pad)
    __bf16* Ehi  = (__bf16*)(h + 2048 + 2 * (size_t)ROWS_ + 2048 + 16);
    __bf16* Emid = Ehi + (size_t)NE_ * 64;
    __bf16* Elo  = Emid + (size_t)NE_ * 64;
    // pre-split weight planes (transposed [N][K]) after tz:
    __bf16* W1h = (__bf16*)(tz + (size_t)B_ * 768);   // 512*64 each
    __bf16* W1m = W1h + (size_t)DENC_ * IN_;
    __bf16* W1l = W1m + (size_t)DENC_ * IN_;
    __bf16* Wrh = W1l + (size_t)DENC_ * IN_;          // 512*512 each
    __bf16* Wrm = Wrh + (size_t)DENC_ * DENC_;
    __bf16* Wrl = Wrm + (size_t)DENC_ * DENC_;
    __bf16* W2h = Wrl + (size_t)DENC_ * DENC_;        // 768*512 each
    __bf16* W2m = W2h + (size_t)768 * DENC_;
    __bf16* W2l = W2m + (size_t)768 * DENC_;
    // activation planes [row][K] bf16 (48MB total), after W2l:
    __bf16* Ahp = W2l + (size_t)768 * DENC_;          // B*512 each
    __bf16* Amp = Ahp + (size_t)B_ * DENC_;
    __bf16* Alp = Amp + (size_t)B_ * DENC_;

    float* t = tz;
    float* z = tz;

    // pre-split weights (transposed bf16 planes)
    k_wsplit<<<(DENC_ * IN_ + 255) / 256, 256, 0, stream>>>(enc_w1, W1h, W1m, W1l, 6, DENC_, DENC_ * IN_);
    k_wsplit<<<(DENC_ * DENC_ + 255) / 256, 256, 0, stream>>>(res_w, Wrh, Wrm, Wrl, 9, DENC_, DENC_ * DENC_);
    k_wsplit<<<(768 * DENC_ + 255) / 256, 256, 0, stream>>>(enc_w2, W2h, W2m, W2l, 9, 768, 768 * DENC_);

    // encoder: gemm1 (f32-A, K=64) -> h; then pre-split h once per producer
    k_gemm_mfma<<<dim3(DENC_ / 64, B_ / 256), 256, 0, stream>>>(x, W1h, W1m, W1l, enc_b1, h, DENC_, IN_);
    k_asplit<<<(B_ * DENC_) / (256 * 8), 256, 0, stream>>>(h, Ahp, Amp, Alp);
    for (int r = 0; r < 2; ++r) {
        k_gemm_mfma_p<<<dim3(DENC_ / 64, B_ / 256), 256, 0, stream>>>(Ahp, Amp, Alp, Wrh, Wrm, Wrl,
                                                                      res_b, t, DENC_, DENC_);
        k_lnrelu<<<B_ / 4, 256, 0, stream>>>(t, h, res_g, res_beta);
        k_asplit<<<(B_ * DENC_) / (256 * 8), 256, 0, stream>>>(h, Ahp, Amp, Alp);
    }
    k_gemm_mfma_p<<<dim3(768 / 64, B_ / 256), 256, 0, stream>>>(Ahp, Amp, Alp, W2h, W2m, W2l,
                                                                enc_b2, z, 768, DENC_);

    // VQ
    hipMemsetAsync(cnts, 0, (NE_ + 16) * sizeof(int), stream);
    k_esplit_fast<<<NE_ / 4, 256, 0, stream>>>(emb, Ehi, Emid, Elo);
    k_esq<<<NE_ / 256, 256, 0, stream>>>(emb, se);
    k_rowsq<<<ROWS_ / 64, 256, 0, stream>>>(z, sz);
    k_distm<<<ROWS_ / 128, 256, 0, stream>>>(z, se, sz, Ehi, Emid, Elo,
                                             idxw, out + IDXF_OFF, lossacc, cnts);
    k_lossperp<<<1, 256, 0, stream>>>(lossacc, cnts, out);
    k_pinv<<<B_, 64, 0, stream>>>(x, emb, idxw, out + COEF_OFF, out + XHAT_OFF);
}

// Round 9
// 777.016 us; speedup vs baseline: 1.0442x; 1.0442x over previous
//
#include <hip/hip_runtime.h>
#include <math.h>

#define B_    16384
#define IN_   64
#define DENC_ 512
#define NE_   2048
#define P_    12
#define ROWS_ 196608      // B_*P_
#define BETA_ 0.25

// output layout (all float32, concatenated in return order)
#define XHAT_OFF 1
#define PERP_OFF 1048577   // 1 + 16384*64
#define IDXF_OFF 1048578
#define COEF_OFF 1245186   // IDXF_OFF + 196608

typedef __bf16 bf16x8 __attribute__((ext_vector_type(8)));
typedef float  f32x16 __attribute__((ext_vector_type(16)));

__device__ __forceinline__ void split3(float v, __bf16& h, __bf16& m, __bf16& l) {
    h = (__bf16)v;
    float r1 = v - (float)h;
    m = (__bf16)r1;
    float r2 = r1 - (float)m;
    l = (__bf16)r2;
}

// async global->LDS 16B per lane; dest = wave-uniform base + lane*16
__device__ __forceinline__ void gload_lds16(const void* g, void* l) {
    __builtin_amdgcn_global_load_lds((const __attribute__((address_space(1))) void*)g,
                                     (__attribute__((address_space(3))) void*)l, 16, 0, 0);
}

// ---------------------------------------------------------------------------
// Pre-split weights: W[K][N] f32 -> Wt planes [N][K] bf16 (hi/mid/lo).
// ---------------------------------------------------------------------------
__global__ void k_wsplit(const float* __restrict__ W,
                         __bf16* __restrict__ Wh, __bf16* __restrict__ Wm,
                         __bf16* __restrict__ Wl, int kshift, int N, int total) {
    int idx = blockIdx.x * 256 + threadIdx.x;
    if (idx < total) {
        int n = idx >> kshift;
        int k = idx & ((1 << kshift) - 1);
        float v = W[(size_t)k * N + n];
        __bf16 h, m, l;
        split3(v, h, m, l);
        Wh[idx] = h; Wm[idx] = m; Wl[idx] = l;
    }
}

// ---------------------------------------------------------------------------
// MFMA GEMM + bias (bf16 3-term split, exact baseline term order per acc).
// 32-COL TILES: block = 256 rows x 32 cols, 4 waves x (64 rows x 32 cols).
// Grid for the K=512 GEMMs rises 512 -> 1024 blocks (was 2/CU, grid-starved
// at 25% occupancy); LDS 24KB/block. Staging = the R7-distm proven pattern
// (coalesced source, one gload per plane per buffer). Per-wave MFMA:ds_read
// stays 4:1. Same A/B fragment values + same per-acc term order as the
// 705us kernel -> bit-identical C. XCD-aware block swizzle kept.
// ---------------------------------------------------------------------------
__global__ __launch_bounds__(256, 2) void k_gemm_mfma(const float* __restrict__ A,
                                                      const __bf16* __restrict__ Bh,
                                                      const __bf16* __restrict__ Bm,
                                                      const __bf16* __restrict__ Bl,
                                                      const float* __restrict__ bias,
                                                      float* __restrict__ C,
                                                      int N, int K) {
    __shared__ __bf16 eS[2][3][32 * 64];   // 24 KB

    // XCD swizzle (bijective: all grids here have nwg % 8 == 0).
    const int nwg  = gridDim.x * gridDim.y;
    const int flat = blockIdx.y * gridDim.x + blockIdx.x;
    const int nf   = (flat & 7) * (nwg >> 3) + (flat >> 3);
    const int bx   = nf % gridDim.x;
    const int by   = nf / gridDim.x;

    const int tid = threadIdx.x;
    const int w = tid >> 6, lane = tid & 63;
    const int r0 = by * 256 + w * 64;
    const int n0 = bx * 32;
    const int lrow = lane & 31;
    const int half = lane >> 5;

    // staging: 256 threads cover 32 cols x 8 granules (16B each), coalesced
    // in 8-lane groups along K; swizzled granule within each 128B col-row.
    const int cc = tid >> 3, qq = tid & 7;
    const size_t off = (size_t)cc * K + (size_t)((qq ^ (cc & 7)) * 8);
    const size_t nbase = (size_t)n0 * K;
    const int ld = w * 512;

    f32x16 acc0, acc1;
#pragma unroll
    for (int i = 0; i < 16; ++i) { acc0[i] = 0.0f; acc1[i] = 0.0f; }

    // prologue: stage chunk 0 into buffer 0
    gload_lds16(Bh + nbase + off, &eS[0][0][ld]);
    gload_lds16(Bm + nbase + off, &eS[0][1][ld]);
    gload_lds16(Bl + nbase + off, &eS[0][2][ld]);

    const int nch = K >> 6;
    for (int ch = 0; ch < nch; ++ch) {
        const int cur = ch & 1;
        __syncthreads();   // drains stage(ch) (issued a full compute phase ago)

        if (ch + 1 < nch) {
            const int nxt = cur ^ 1;
            const size_t b = nbase + (size_t)(ch + 1) * 64;
            gload_lds16(Bh + b + off, &eS[nxt][0][ld]);
            gload_lds16(Bm + b + off, &eS[nxt][1][ld]);
            gload_lds16(Bl + b + off, &eS[nxt][2][ld]);
        }

        // A fragments for this chunk: split f32 rows in-register (2 rowblocks)
        bf16x8 ah0[4], am0[4], al0[4], ah1[4], am1[4], al1[4];
        {
            const float* ar0 = A + (size_t)(r0 + lrow) * K + ch * 64 + half * 8;
            const float* ar1 = ar0 + (size_t)32 * K;
#pragma unroll
            for (int kc = 0; kc < 4; ++kc) {
                float4 u0 = *(const float4*)(ar0 + kc * 16);
                float4 u1 = *(const float4*)(ar0 + kc * 16 + 4);
                float va[8] = {u0.x, u0.y, u0.z, u0.w, u1.x, u1.y, u1.z, u1.w};
                float4 t0 = *(const float4*)(ar1 + kc * 16);
                float4 t1 = *(const float4*)(ar1 + kc * 16 + 4);
                float vb[8] = {t0.x, t0.y, t0.z, t0.w, t1.x, t1.y, t1.z, t1.w};
#pragma unroll
                for (int j = 0; j < 8; ++j) {
                    __bf16 hh, mm, ll;
                    split3(va[j], hh, mm, ll);
                    ah0[kc][j] = hh; am0[kc][j] = mm; al0[kc][j] = ll;
                    split3(vb[j], hh, mm, ll);
                    ah1[kc][j] = hh; am1[kc][j] = mm; al1[kc][j] = ll;
                }
            }
        }

#pragma unroll
        for (int kc = 0; kc < 4; ++kc) {
            const int q = kc * 2 + half;
            const int g = (q ^ (lrow & 7)) * 8;
            bf16x8 bh = *(const bf16x8*)(&eS[cur][0][lrow * 64 + g]);
            bf16x8 bm = *(const bf16x8*)(&eS[cur][1][lrow * 64 + g]);
            bf16x8 bl = *(const bf16x8*)(&eS[cur][2][lrow * 64 + g]);

            acc0 = __builtin_amdgcn_mfma_f32_32x32x16_bf16(ah0[kc], bh, acc0, 0, 0, 0);
            acc1 = __builtin_amdgcn_mfma_f32_32x32x16_bf16(ah1[kc], bh, acc1, 0, 0, 0);
            acc0 = __builtin_amdgcn_mfma_f32_32x32x16_bf16(ah0[kc], bm, acc0, 0, 0, 0);
            acc1 = __builtin_amdgcn_mfma_f32_32x32x16_bf16(ah1[kc], bm, acc1, 0, 0, 0);
            acc0 = __builtin_amdgcn_mfma_f32_32x32x16_bf16(am0[kc], bh, acc0, 0, 0, 0);
            acc1 = __builtin_amdgcn_mfma_f32_32x32x16_bf16(am1[kc], bh, acc1, 0, 0, 0);
            acc0 = __builtin_amdgcn_mfma_f32_32x32x16_bf16(ah0[kc], bl, acc0, 0, 0, 0);
            acc1 = __builtin_amdgcn_mfma_f32_32x32x16_bf16(ah1[kc], bl, acc1, 0, 0, 0);
            acc0 = __builtin_amdgcn_mfma_f32_32x32x16_bf16(am0[kc], bm, acc0, 0, 0, 0);
            acc1 = __builtin_amdgcn_mfma_f32_32x32x16_bf16(am1[kc], bm, acc1, 0, 0, 0);
            acc0 = __builtin_amdgcn_mfma_f32_32x32x16_bf16(al0[kc], bh, acc0, 0, 0, 0);
            acc1 = __builtin_amdgcn_mfma_f32_32x32x16_bf16(al1[kc], bh, acc1, 0, 0, 0);
        }
    }

    const int col = n0 + lrow;
    const float bv = bias[col];
#pragma unroll
    for (int r = 0; r < 16; ++r) {
        int rr = (r & 3) + 8 * (r >> 2) + 4 * half;
        C[(size_t)(r0 + rr) * N + col] = acc0[r] + bv;
        C[(size_t)(r0 + 32 + rr) * N + col] = acc1[r] + bv;
    }
}

// ---------------------------------------------------------------------------
// h = h + relu(layer_norm(t) * g + beta)
// ---------------------------------------------------------------------------
__global__ __launch_bounds__(256) void k_lnrelu(const float* __restrict__ t,
                                                float* __restrict__ h,
                                                const float* __restrict__ g,
                                                const float* __restrict__ beta) {
    const int tid = threadIdx.x;
    const int wv = tid >> 6, lane = tid & 63;
    const int row = blockIdx.x * 4 + wv;
    const float* tr = t + (size_t)row * DENC_;
    float* hr = h + (size_t)row * DENC_;

    float4 v0 = *(const float4*)(tr + lane * 4);
    float4 v1 = *(const float4*)(tr + 256 + lane * 4);

    float s = v0.x + v0.y + v0.z + v0.w + v1.x + v1.y + v1.z + v1.w;
#pragma unroll
    for (int m = 1; m < 64; m <<= 1) s += __shfl_xor(s, m);
    float mu = s / 512.0f;

    float d0x = v0.x - mu, d0y = v0.y - mu, d0z = v0.z - mu, d0w = v0.w - mu;
    float d1x = v1.x - mu, d1y = v1.y - mu, d1z = v1.z - mu, d1w = v1.w - mu;
    float vs = d0x * d0x + d0y * d0y + d0z * d0z + d0w * d0w +
               d1x * d1x + d1y * d1y + d1z * d1z + d1w * d1w;
#pragma unroll
    for (int m = 1; m < 64; m <<= 1) vs += __shfl_xor(vs, m);
    float var = vs / 512.0f;
    float rs = (float)(1.0 / sqrt((double)var + 1e-5));

    float4 g0 = *(const float4*)(g + lane * 4);
    float4 g1 = *(const float4*)(g + 256 + lane * 4);
    float4 b0 = *(const float4*)(beta + lane * 4);
    float4 b1 = *(const float4*)(beta + 256 + lane * 4);

    float4 h0 = *(float4*)(hr + lane * 4);
    float4 h1 = *(float4*)(hr + 256 + lane * 4);

    h0.x += fmaxf(d0x * rs * g0.x + b0.x, 0.0f);
    h0.y += fmaxf(d0y * rs * g0.y + b0.y, 0.0f);
    h0.z += fmaxf(d0z * rs * g0.z + b0.z, 0.0f);
    h0.w += fmaxf(d0w * rs * g0.w + b0.w, 0.0f);
    h1.x += fmaxf(d1x * rs * g1.x + b1.x, 0.0f);
    h1.y += fmaxf(d1y * rs * g1.y + b1.y, 0.0f);
    h1.z += fmaxf(d1z * rs * g1.z + b1.z, 0.0f);
    h1.w += fmaxf(d1w * rs * g1.w + b1.w, 0.0f);

    *(float4*)(hr + lane * 4) = h0;
    *(float4*)(hr + 256 + lane * 4) = h1;
}

// ---------------------------------------------------------------------------
// Codebook split (coalesced) + se
// ---------------------------------------------------------------------------
__global__ __launch_bounds__(256) void k_esplit_fast(const float* __restrict__ emb,
                                                     __bf16* __restrict__ Ehi,
                                                     __bf16* __restrict__ Emid,
                                                     __bf16* __restrict__ Elo) {
    const int wv = threadIdx.x >> 6, lane = threadIdx.x & 63;
    const int c = blockIdx.x * 4 + wv;
    float v = emb[(size_t)c * 64 + lane];
    __bf16 h, m, l;
    split3(v, h, m, l);
    Ehi[(size_t)c * 64 + lane] = h;
    Emid[(size_t)c * 64 + lane] = m;
    Elo[(size_t)c * 64 + lane] = l;
}

__global__ void k_esq(const float* __restrict__ emb, float* __restrict__ se) {
    int t = blockIdx.x * 256 + threadIdx.x;
    if (t < NE_) {
        float s = 0.0f;
        for (int k = 0; k < 64; ++k) {
            float v = emb[(size_t)t * 64 + k];
            s += v * v;
        }
        se[t] = s;
    }
}

// ---------------------------------------------------------------------------
// sz[row] = sum(z[row]^2)
// ---------------------------------------------------------------------------
__global__ __launch_bounds__(256) void k_rowsq(const float* __restrict__ z,
                                               float* __restrict__ sz) {
    const int tid = threadIdx.x;
    const int row = blockIdx.x * 64 + (tid >> 2);
    const int part = tid & 3;
    const float4* zp = (const float4*)(z + (size_t)row * 64) + part * 4;
    float s = 0.0f;
#pragma unroll
    for (int i = 0; i < 4; ++i) {
        float4 v = zp[i];
        s += v.x * v.x + v.y * v.y + v.z * v.z + v.w * v.w;
    }
    s += __shfl_xor(s, 1);
    s += __shfl_xor(s, 2);
    if (part == 0) sz[row] = s;
}

// ---------------------------------------------------------------------------
// MFMA distance + argmin: R7 verbatim (293us known-good). 24KB LDS,
// 32-col chunks, [col][granule-XOR] layout, coalesced staging source.
// ---------------------------------------------------------------------------
__global__ __launch_bounds__(256) void k_distm(const float* __restrict__ z,
                                               const float* __restrict__ se,
                                               const float* __restrict__ sz,
                                               const __bf16* __restrict__ Ehi,
                                               const __bf16* __restrict__ Emid,
                                               const __bf16* __restrict__ Elo,
                                               int* __restrict__ idxw,
                                               float* __restrict__ idxf,
                                               float* __restrict__ lossacc,
                                               int* __restrict__ counts) {
    __shared__ __bf16 eS[2][3][32 * 64];   // 24 KB

    const int tid = threadIdx.x;
    const int w = tid >> 6, lane = tid & 63;
    const int r0 = blockIdx.x * 128 + w * 32;
    const int lrow = lane & 31;
    const int half = lane >> 5;

    // staging: 256 threads x 16B = one 32x64 bf16 plane (4KB) per gload
    const int cc = tid >> 3, qq = tid & 7;
    const int off = cc * 64 + (qq ^ (cc & 7)) * 8;
    const int ld = w * 512;

    // persistent A fragments (3-way split of z rows)
    bf16x8 ah[4], am[4], al[4];
    {
        const float* zr = z + (size_t)(r0 + lrow) * 64 + half * 8;
#pragma unroll
        for (int kc = 0; kc < 4; ++kc) {
            float4 u0 = *(const float4*)(zr + kc * 16);
            float4 u1 = *(const float4*)(zr + kc * 16 + 4);
            float v[8] = {u0.x, u0.y, u0.z, u0.w, u1.x, u1.y, u1.z, u1.w};
#pragma unroll
            for (int j = 0; j < 8; ++j) {
                __bf16 hh, mm, ll;
                split3(v[j], hh, mm, ll);
                ah[kc][j] = hh; am[kc][j] = mm; al[kc][j] = ll;
            }
        }
    }

    float szv[16];
#pragma unroll
    for (int r = 0; r < 16; ++r) {
        int rl = (r & 3) + 8 * (r >> 2) + 4 * half;
        szv[r] = sz[r0 + rl];
    }

    float bd[16];
    int bi[16];
#pragma unroll
    for (int r = 0; r < 16; ++r) { bd[r] = 1e30f; bi[r] = 0; }

    // prologue: stage chunk 0 into buffer 0
    gload_lds16(Ehi + off, &eS[0][0][ld]);
    gload_lds16(Emid + off, &eS[0][1][ld]);
    gload_lds16(Elo + off, &eS[0][2][ld]);

    for (int ch = 0; ch < 64; ++ch) {
        const int cur = ch & 1;
        __syncthreads();   // drains stage(ch); issued a full compute phase ago

        if (ch + 1 < 64) {
            const int nxt = cur ^ 1;
            const int b = (ch + 1) * 2048;
            gload_lds16(Ehi + b + off, &eS[nxt][0][ld]);
            gload_lds16(Emid + b + off, &eS[nxt][1][ld]);
            gload_lds16(Elo + b + off, &eS[nxt][2][ld]);
        }

        f32x16 acc;
#pragma unroll
        for (int i = 0; i < 16; ++i) acc[i] = 0.0f;

#pragma unroll
        for (int kc = 0; kc < 4; ++kc) {
            const int q = kc * 2 + half;
            const int g = (q ^ (lrow & 7)) * 8;
            bf16x8 bh = *(const bf16x8*)(&eS[cur][0][lrow * 64 + g]);
            bf16x8 bm = *(const bf16x8*)(&eS[cur][1][lrow * 64 + g]);
            bf16x8 bl = *(const bf16x8*)(&eS[cur][2][lrow * 64 + g]);

            acc = __builtin_amdgcn_mfma_f32_32x32x16_bf16(ah[kc], bh, acc, 0, 0, 0);
            acc = __builtin_amdgcn_mfma_f32_32x32x16_bf16(ah[kc], bm, acc, 0, 0, 0);
            acc = __builtin_amdgcn_mfma_f32_32x32x16_bf16(am[kc], bh, acc, 0, 0, 0);
            acc = __builtin_amdgcn_mfma_f32_32x32x16_bf16(ah[kc], bl, acc, 0, 0, 0);
            acc = __builtin_amdgcn_mfma_f32_32x32x16_bf16(am[kc], bm, acc, 0, 0, 0);
            acc = __builtin_amdgcn_mfma_f32_32x32x16_bf16(al[kc], bh, acc, 0, 0, 0);
        }

        const int c0 = ch * 32;
        const float se0 = se[c0 + lrow];
        const int   ci0 = c0 + lrow;
#pragma unroll
        for (int r = 0; r < 16; ++r) {
            float d0 = fmaf(-2.0f, acc[r], szv[r] + se0);
            if (d0 < bd[r]) { bd[r] = d0; bi[r] = ci0; }
        }
    }

    // cross-lane argmin within each 32-lane half (lexicographic: d, then idx)
#pragma unroll
    for (int r = 0; r < 16; ++r) {
        float d = bd[r];
        int i = bi[r];
#pragma unroll
        for (int off2 = 1; off2 < 32; off2 <<= 1) {
            float od = __shfl_xor(d, off2);
            int oi = __shfl_xor(i, off2);
            if (od < d || (od == d && oi < i)) { d = od; i = oi; }
        }
        bd[r] = d; bi[r] = i;
    }

    if (lrow == 0) {
        float lsum = 0.0f;
#pragma unroll
        for (int r = 0; r < 16; ++r) {
            int rl = (r & 3) + 8 * (r >> 2) + 4 * half;
            int row = r0 + rl;
            idxw[row] = bi[r];
            idxf[row] = (float)bi[r];
            lsum += bd[r];
            atomicAdd(&counts[bi[r]], 1);
        }
        atomicAdd(lossacc, lsum);
    }
}

// ---------------------------------------------------------------------------
// loss (from accumulated dmin sum) + perplexity (from counts)
// ---------------------------------------------------------------------------
__global__ __launch_bounds__(256) void k_lossperp(const float* __restrict__ lossacc,
                                                  const int* __restrict__ counts,
                                                  float* __restrict__ out) {
    __shared__ double red[256];
    const int tid = threadIdx.x;

    double hsum = 0.0;
    for (int i = tid; i < NE_; i += 256) {
        float p = (float)counts[i] / 196608.0f;
        float lg = logf(p + 1e-10f);
        hsum += (double)(p * lg);
    }
    red[tid] = hsum;
    __syncthreads();
    for (int off = 128; off > 0; off >>= 1) {
        if (tid < off) red[tid] += red[tid + off];
        __syncthreads();
    }
    if (tid == 0) {
        out[PERP_OFF] = (float)exp(-red[0]);
        out[0] = (float)((double)lossacc[0] * (1.0 + BETA_) / ((double)ROWS_ * IN_));
    }
}

// ---------------------------------------------------------------------------
// per-block pinv least-squares (single-wave workgroup)
// ---------------------------------------------------------------------------
__global__ __launch_bounds__(64) void k_pinv(const float* __restrict__ xin,
                                             const float* __restrict__ emb,
                                             const int* __restrict__ idxw,
                                             float* __restrict__ coeff,
                                             float* __restrict__ xhat) {
    __shared__ float aS[12][65];
    __shared__ float xS[64];
    __shared__ double GS[12][12];
    __shared__ double bS[12];
    __shared__ double yS[12];
    __shared__ double uS[12];
    __shared__ float cS[12];

    const int lane = threadIdx.x;
    const int b = blockIdx.x;

    int my = 0;
    if (lane < 12) my = idxw[(size_t)b * 12 + lane];
    int id[12];
#pragma unroll
    for (int p = 0; p < 12; ++p) id[p] = __shfl(my, p);

    int rep = lane, mcnt = 1;
    if (lane < 12) {
        rep = -1;
        mcnt = 0;
        for (int q = 0; q < 12; ++q) {
            if (id[q] == id[lane]) {
                if (rep < 0) rep = q;
                mcnt++;
            }
        }
    }

#pragma unroll
    for (int p = 0; p < 12; ++p) aS[p][lane] = emb[(size_t)id[p] * 64 + lane];
    xS[lane] = xin[(size_t)b * 64 + lane];
    __syncthreads();

    for (int item = lane; item < 90; item += 64) {
        if (item < 78) {
            int j = 0, k = 0, c = item;
            for (j = 0; j < 12; ++j) {
                int cnt = 12 - j;
                if (c < cnt) { k = j + c; break; }
                c -= cnt;
            }
            double s = 0.0;
            for (int t = 0; t < 64; ++t) s += (double)aS[j][t] * (double)aS[k][t];
            GS[j][k] = s;
            GS[k][j] = s;
        } else {
            int j = item - 78;
            double s = 0.0;
            for (int t = 0; t < 64; ++t) s += (double)aS[j][t] * (double)xS[t];
            bS[j] = s;
        }
    }
    __syncthreads();

    if (lane == 0) {
        for (int p = 0; p < 12; ++p) {
            int rp = -1;
            for (int q = 0; q < 12; ++q) {
                if (id[q] == id[p]) { rp = q; break; }
            }
            if (rp != p) {
                for (int q = 0; q < 12; ++q) {
                    GS[p][q] = 0.0;
                    GS[q][p] = 0.0;
                }
                GS[p][p] = 1.0;
                bS[p] = 0.0;
            }
        }
    }
    __syncthreads();

    for (int j = 0; j < 12; ++j) {
        if (lane == j) {
            double s = GS[j][j];
            for (int k = 0; k < j; ++k) {
                double l = GS[j][k];
                s -= l * l;
            }
            GS[j][j] = sqrt(fmax(s, 1e-30));
        }
        __syncthreads();
        if (lane > j && lane < 12) {
            double s = GS[lane][j];
            for (int k = 0; k < j; ++k) s -= GS[lane][k] * GS[j][k];
            GS[lane][j] = s / GS[j][j];
        }
        __syncthreads();
    }

    double s = (lane < 12) ? bS[lane] : 0.0;
    for (int k = 0; k < 12; ++k) {
        if (lane == k) yS[k] = s / GS[k][k];
        __syncthreads();
        double yk = yS[k];
        if (lane > k && lane < 12) s -= GS[lane][k] * yk;
    }
    double tacc = 0.0;
    for (int k = 11; k >= 0; --k) {
        if (lane == k) uS[k] = (yS[k] - tacc) / GS[k][k];
        __syncthreads();
        double uk = uS[k];
        if (lane < k) tacc += GS[k][lane] * uk;
    }
    __syncthreads();

    if (lane < 12) {
        double c = uS[rep] / (double)mcnt;
        coeff[(size_t)b * 12 + lane] = (float)c;
        cS[lane] = (float)c;
    }
    __syncthreads();

    float sx = 0.0f;
#pragma unroll
    for (int p = 0; p < 12; ++p) sx += aS[p][lane] * cS[p];
    xhat[(size_t)b * 64 + lane] = sx;
}

// ---------------------------------------------------------------------------

extern "C" void kernel_launch(void* const* d_in, const int* in_sizes, int n_in,
                              void* d_out, int out_size, void* d_ws, size_t ws_size,
                              hipStream_t stream) {
    const float* x        = (const float*)d_in[0];
    const float* enc_w1   = (const float*)d_in[1];
    const float* enc_b1   = (const float*)d_in[2];
    const float* res_w    = (const float*)d_in[3];
    const float* res_b    = (const float*)d_in[4];
    const float* res_g    = (const float*)d_in[5];
    const float* res_beta = (const float*)d_in[6];
    const float* enc_w2   = (const float*)d_in[7];
    const float* enc_b2   = (const float*)d_in[8];
    const float* emb      = (const float*)d_in[9];

    float* out = (float*)d_out;

    // workspace layout
    float* h  = (float*)d_ws;            // B*512 f32 (32MB), reused after enc2
    float* tz = h + (size_t)B_ * DENC_;  // B*768 f32 (48MB): t then z
    // VQ scratch overlapping h (dead after enc2):
    float* se    = h;                                        // 2048
    float* sz    = h + 2048;                                 // ROWS_
    int*   idxw  = (int*)(h + 2048 + (size_t)ROWS_);         // ROWS_
    int*   cnts  = (int*)(h + 2048 + 2 * (size_t)ROWS_);     // 2048
    float* lossacc = (float*)(cnts + NE_);                   // 1 (+pad)
    __bf16* Ehi  = (__bf16*)(h + 2048 + 2 * (size_t)ROWS_ + 2048 + 16);
    __bf16* Emid = Ehi + (size_t)NE_ * 64;
    __bf16* Elo  = Emid + (size_t)NE_ * 64;
    // pre-split weight planes (transposed [N][K]) after tz:
    __bf16* W1h = (__bf16*)(tz + (size_t)B_ * 768);   // 512*64 each
    __bf16* W1m = W1h + (size_t)DENC_ * IN_;
    __bf16* W1l = W1m + (size_t)DENC_ * IN_;
    __bf16* Wrh = W1l + (size_t)DENC_ * IN_;          // 512*512 each
    __bf16* Wrm = Wrh + (size_t)DENC_ * DENC_;
    __bf16* Wrl = Wrm + (size_t)DENC_ * DENC_;
    __bf16* W2h = Wrl + (size_t)DENC_ * DENC_;        // 768*512 each
    __bf16* W2m = W2h + (size_t)768 * DENC_;
    __bf16* W2l = W2m + (size_t)768 * DENC_;

    float* t = tz;
    float* z = tz;

    // pre-split weights (transposed bf16 planes)
    k_wsplit<<<(DENC_ * IN_ + 255) / 256, 256, 0, stream>>>(enc_w1, W1h, W1m, W1l, 6, DENC_, DENC_ * IN_);
    k_wsplit<<<(DENC_ * DENC_ + 255) / 256, 256, 0, stream>>>(res_w, Wrh, Wrm, Wrl, 9, DENC_, DENC_ * DENC_);
    k_wsplit<<<(768 * DENC_ + 255) / 256, 256, 0, stream>>>(enc_w2, W2h, W2m, W2l, 9, 768, 768 * DENC_);

    // encoder (MFMA path, 256x32 tiles, double-buffered, XCD-swizzled)
    k_gemm_mfma<<<dim3(DENC_ / 32, B_ / 256), 256, 0, stream>>>(x, W1h, W1m, W1l, enc_b1, h, DENC_, IN_);
    for (int r = 0; r < 2; ++r) {
        k_gemm_mfma<<<dim3(DENC_ / 32, B_ / 256), 256, 0, stream>>>(h, Wrh, Wrm, Wrl, res_b, t, DENC_, DENC_);
        k_lnrelu<<<B_ / 4, 256, 0, stream>>>(t, h, res_g, res_beta);
    }
    k_gemm_mfma<<<dim3(768 / 32, B_ / 256), 256, 0, stream>>>(h, W2h, W2m, W2l, enc_b2, z, 768, DENC_);

    // VQ
    hipMemsetAsync(cnts, 0, (NE_ + 16) * sizeof(int), stream);
    k_esplit_fast<<<NE_ / 4, 256, 0, stream>>>(emb, Ehi, Emid, Elo);
    k_esq<<<NE_ / 256, 256, 0, stream>>>(emb, se);
    k_rowsq<<<ROWS_ / 64, 256, 0, stream>>>(z, sz);
    k_distm<<<ROWS_ / 128, 256, 0, stream>>>(z, se, sz, Ehi, Emid, Elo,
                                             idxw, out + IDXF_OFF, lossacc, cnts);
    k_lossperp<<<1, 256, 0, stream>>>(lossacc, cnts, out);
    k_pinv<<<B_, 64, 0, stream>>>(x, emb, idxw, out + COEF_OFF, out + XHAT_OFF);
}

// Round 10
// 721.628 us; speedup vs baseline: 1.1243x; 1.0768x over previous
//
#include <hip/hip_runtime.h>
#include <math.h>

#define B_    16384
#define IN_   64
#define DENC_ 512
#define NE_   2048
#define P_    12
#define ROWS_ 196608      // B_*P_
#define BETA_ 0.25

// output layout (all float32, concatenated in return order)
#define XHAT_OFF 1
#define PERP_OFF 1048577   // 1 + 16384*64
#define IDXF_OFF 1048578
#define COEF_OFF 1245186   // IDXF_OFF + 196608

typedef __bf16 bf16x8 __attribute__((ext_vector_type(8)));
typedef float  f32x16 __attribute__((ext_vector_type(16)));

__device__ __forceinline__ void split3(float v, __bf16& h, __bf16& m, __bf16& l) {
    h = (__bf16)v;
    float r1 = v - (float)h;
    m = (__bf16)r1;
    float r2 = r1 - (float)m;
    l = (__bf16)r2;
}

// async global->LDS 16B per lane; dest = wave-uniform base + lane*16
__device__ __forceinline__ void gload_lds16(const void* g, void* l) {
    __builtin_amdgcn_global_load_lds((const __attribute__((address_space(1))) void*)g,
                                     (__attribute__((address_space(3))) void*)l, 16, 0, 0);
}

// ---------------------------------------------------------------------------
// Pre-split weights: W[K][N] f32 -> Wt planes [N][K] bf16 (hi/mid/lo).
// ---------------------------------------------------------------------------
__global__ void k_wsplit(const float* __restrict__ W,
                         __bf16* __restrict__ Wh, __bf16* __restrict__ Wm,
                         __bf16* __restrict__ Wl, int kshift, int N, int total) {
    int idx = blockIdx.x * 256 + threadIdx.x;
    if (idx < total) {
        int n = idx >> kshift;
        int k = idx & ((1 << kshift) - 1);
        float v = W[(size_t)k * N + n];
        __bf16 h, m, l;
        split3(v, h, m, l);
        Wh[idx] = h; Wm[idx] = m; Wl[idx] = l;
    }
}

// ---------------------------------------------------------------------------
// MFMA GEMM + bias (bf16 3-term split, exact baseline term order per acc),
// 64 rows/wave (2 rowblocks), block = 256 rows x 64 cols. Double-buffered
// LDS + global_load_lds staging. XCD-aware block swizzle (R6: ~-45us).
// R7-verbatim (known-good). Bit-identical C.
// ---------------------------------------------------------------------------
__global__ __launch_bounds__(256, 2) void k_gemm_mfma(const float* __restrict__ A,
                                                      const __bf16* __restrict__ Bh,
                                                      const __bf16* __restrict__ Bm,
                                                      const __bf16* __restrict__ Bl,
                                                      const float* __restrict__ bias,
                                                      float* __restrict__ C,
                                                      int N, int K) {
    __shared__ __bf16 eS[2][3][64 * 64];   // 48 KB

    // XCD swizzle (bijective: all grids here have nwg % 8 == 0).
    const int nwg  = gridDim.x * gridDim.y;
    const int flat = blockIdx.y * gridDim.x + blockIdx.x;
    const int nf   = (flat & 7) * (nwg >> 3) + (flat >> 3);
    const int bx   = nf % gridDim.x;
    const int by   = nf / gridDim.x;

    const int tid = threadIdx.x;
    const int w = tid >> 6, lane = tid & 63;
    const int r0 = by * 256 + w * 64;
    const int n0 = bx * 64;
    const int lrow = lane & 31;
    const int half = lane >> 5;

    const int cc0 = tid >> 3, qq = tid & 7;
    const int cc1 = cc0 + 32;
    const size_t off0 = (size_t)cc0 * K + (size_t)((qq ^ (cc0 & 7)) * 8);
    const size_t off1 = (size_t)cc1 * K + (size_t)((qq ^ (cc1 & 7)) * 8);
    const size_t nbase = (size_t)n0 * K;
    const int ld0 = w * 512;
    const int ld1 = 2048 + w * 512;

    f32x16 acc00, acc01, acc10, acc11;
#pragma unroll
    for (int i = 0; i < 16; ++i) { acc00[i] = 0.0f; acc01[i] = 0.0f; acc10[i] = 0.0f; acc11[i] = 0.0f; }

    {
        const size_t b = nbase;
        gload_lds16(Bh + b + off0, &eS[0][0][ld0]);
        gload_lds16(Bh + b + off1, &eS[0][0][ld1]);
        gload_lds16(Bm + b + off0, &eS[0][1][ld0]);
        gload_lds16(Bm + b + off1, &eS[0][1][ld1]);
        gload_lds16(Bl + b + off0, &eS[0][2][ld0]);
        gload_lds16(Bl + b + off1, &eS[0][2][ld1]);
    }

    const int nch = K >> 6;
    for (int ch = 0; ch < nch; ++ch) {
        const int cur = ch & 1;
        __syncthreads();

        if (ch + 1 < nch) {
            const int nxt = cur ^ 1;
            const size_t b = nbase + (size_t)(ch + 1) * 64;
            gload_lds16(Bh + b + off0, &eS[nxt][0][ld0]);
            gload_lds16(Bh + b + off1, &eS[nxt][0][ld1]);
            gload_lds16(Bm + b + off0, &eS[nxt][1][ld0]);
            gload_lds16(Bm + b + off1, &eS[nxt][1][ld1]);
            gload_lds16(Bl + b + off0, &eS[nxt][2][ld0]);
            gload_lds16(Bl + b + off1, &eS[nxt][2][ld1]);
        }

        bf16x8 ah0[4], am0[4], al0[4], ah1[4], am1[4], al1[4];
        {
            const float* ar0 = A + (size_t)(r0 + lrow) * K + ch * 64 + half * 8;
            const float* ar1 = ar0 + (size_t)32 * K;
#pragma unroll
            for (int kc = 0; kc < 4; ++kc) {
                float4 u0 = *(const float4*)(ar0 + kc * 16);
                float4 u1 = *(const float4*)(ar0 + kc * 16 + 4);
                float va[8] = {u0.x, u0.y, u0.z, u0.w, u1.x, u1.y, u1.z, u1.w};
                float4 t0 = *(const float4*)(ar1 + kc * 16);
                float4 t1 = *(const float4*)(ar1 + kc * 16 + 4);
                float vb[8] = {t0.x, t0.y, t0.z, t0.w, t1.x, t1.y, t1.z, t1.w};
#pragma unroll
                for (int j = 0; j < 8; ++j) {
                    __bf16 hh, mm, ll;
                    split3(va[j], hh, mm, ll);
                    ah0[kc][j] = hh; am0[kc][j] = mm; al0[kc][j] = ll;
                    split3(vb[j], hh, mm, ll);
                    ah1[kc][j] = hh; am1[kc][j] = mm; al1[kc][j] = ll;
                }
            }
        }

#pragma unroll
        for (int kc = 0; kc < 4; ++kc) {
            const int q = kc * 2 + half;
            const int g = (q ^ (lrow & 7)) * 8;
            bf16x8 b0h = *(const bf16x8*)(&eS[cur][0][lrow * 64 + g]);
            bf16x8 b0m = *(const bf16x8*)(&eS[cur][1][lrow * 64 + g]);
            bf16x8 b0l = *(const bf16x8*)(&eS[cur][2][lrow * 64 + g]);
            bf16x8 b1h = *(const bf16x8*)(&eS[cur][0][(lrow + 32) * 64 + g]);
            bf16x8 b1m = *(const bf16x8*)(&eS[cur][1][(lrow + 32) * 64 + g]);
            bf16x8 b1l = *(const bf16x8*)(&eS[cur][2][(lrow + 32) * 64 + g]);

            acc00 = __builtin_amdgcn_mfma_f32_32x32x16_bf16(ah0[kc], b0h, acc00, 0, 0, 0);
            acc01 = __builtin_amdgcn_mfma_f32_32x32x16_bf16(ah0[kc], b1h, acc01, 0, 0, 0);
            acc10 = __builtin_amdgcn_mfma_f32_32x32x16_bf16(ah1[kc], b0h, acc10, 0, 0, 0);
            acc11 = __builtin_amdgcn_mfma_f32_32x32x16_bf16(ah1[kc], b1h, acc11, 0, 0, 0);
            acc00 = __builtin_amdgcn_mfma_f32_32x32x16_bf16(ah0[kc], b0m, acc00, 0, 0, 0);
            acc01 = __builtin_amdgcn_mfma_f32_32x32x16_bf16(ah0[kc], b1m, acc01, 0, 0, 0);
            acc10 = __builtin_amdgcn_mfma_f32_32x32x16_bf16(ah1[kc], b0m, acc10, 0, 0, 0);
            acc11 = __builtin_amdgcn_mfma_f32_32x32x16_bf16(ah1[kc], b1m, acc11, 0, 0, 0);
            acc00 = __builtin_amdgcn_mfma_f32_32x32x16_bf16(am0[kc], b0h, acc00, 0, 0, 0);
            acc01 = __builtin_amdgcn_mfma_f32_32x32x16_bf16(am0[kc], b1h, acc01, 0, 0, 0);
            acc10 = __builtin_amdgcn_mfma_f32_32x32x16_bf16(am1[kc], b0h, acc10, 0, 0, 0);
            acc11 = __builtin_amdgcn_mfma_f32_32x32x16_bf16(am1[kc], b1h, acc11, 0, 0, 0);
            acc00 = __builtin_amdgcn_mfma_f32_32x32x16_bf16(ah0[kc], b0l, acc00, 0, 0, 0);
            acc01 = __builtin_amdgcn_mfma_f32_32x32x16_bf16(ah0[kc], b1l, acc01, 0, 0, 0);
            acc10 = __builtin_amdgcn_mfma_f32_32x32x16_bf16(ah1[kc], b0l, acc10, 0, 0, 0);
            acc11 = __builtin_amdgcn_mfma_f32_32x32x16_bf16(ah1[kc], b1l, acc11, 0, 0, 0);
            acc00 = __builtin_amdgcn_mfma_f32_32x32x16_bf16(am0[kc], b0m, acc00, 0, 0, 0);
            acc01 = __builtin_amdgcn_mfma_f32_32x32x16_bf16(am0[kc], b1m, acc01, 0, 0, 0);
            acc10 = __builtin_amdgcn_mfma_f32_32x32x16_bf16(am1[kc], b0m, acc10, 0, 0, 0);
            acc11 = __builtin_amdgcn_mfma_f32_32x32x16_bf16(am1[kc], b1m, acc11, 0, 0, 0);
            acc00 = __builtin_amdgcn_mfma_f32_32x32x16_bf16(al0[kc], b0h, acc00, 0, 0, 0);
            acc01 = __builtin_amdgcn_mfma_f32_32x32x16_bf16(al0[kc], b1h, acc01, 0, 0, 0);
            acc10 = __builtin_amdgcn_mfma_f32_32x32x16_bf16(al1[kc], b0h, acc10, 0, 0, 0);
            acc11 = __builtin_amdgcn_mfma_f32_32x32x16_bf16(al1[kc], b1h, acc11, 0, 0, 0);
        }
    }

    const int col0 = n0 + lrow, col1 = col0 + 32;
    const float bv0 = bias[col0], bv1 = bias[col1];
#pragma unroll
    for (int r = 0; r < 16; ++r) {
        int rr = (r & 3) + 8 * (r >> 2) + 4 * half;
        C[(size_t)(r0 + rr) * N + col0] = acc00[r] + bv0;
        C[(size_t)(r0 + rr) * N + col1] = acc01[r] + bv1;
        C[(size_t)(r0 + 32 + rr) * N + col0] = acc10[r] + bv0;
        C[(size_t)(r0 + 32 + rr) * N + col1] = acc11[r] + bv1;
    }
}

// ---------------------------------------------------------------------------
// h = h + relu(layer_norm(t) * g + beta)
// ---------------------------------------------------------------------------
__global__ __launch_bounds__(256) void k_lnrelu(const float* __restrict__ t,
                                                float* __restrict__ h,
                                                const float* __restrict__ g,
                                                const float* __restrict__ beta) {
    const int tid = threadIdx.x;
    const int wv = tid >> 6, lane = tid & 63;
    const int row = blockIdx.x * 4 + wv;
    const float* tr = t + (size_t)row * DENC_;
    float* hr = h + (size_t)row * DENC_;

    float4 v0 = *(const float4*)(tr + lane * 4);
    float4 v1 = *(const float4*)(tr + 256 + lane * 4);

    float s = v0.x + v0.y + v0.z + v0.w + v1.x + v1.y + v1.z + v1.w;
#pragma unroll
    for (int m = 1; m < 64; m <<= 1) s += __shfl_xor(s, m);
    float mu = s / 512.0f;

    float d0x = v0.x - mu, d0y = v0.y - mu, d0z = v0.z - mu, d0w = v0.w - mu;
    float d1x = v1.x - mu, d1y = v1.y - mu, d1z = v1.z - mu, d1w = v1.w - mu;
    float vs = d0x * d0x + d0y * d0y + d0z * d0z + d0w * d0w +
               d1x * d1x + d1y * d1y + d1z * d1z + d1w * d1w;
#pragma unroll
    for (int m = 1; m < 64; m <<= 1) vs += __shfl_xor(vs, m);
    float var = vs / 512.0f;
    float rs = (float)(1.0 / sqrt((double)var + 1e-5));

    float4 g0 = *(const float4*)(g + lane * 4);
    float4 g1 = *(const float4*)(g + 256 + lane * 4);
    float4 b0 = *(const float4*)(beta + lane * 4);
    float4 b1 = *(const float4*)(beta + 256 + lane * 4);

    float4 h0 = *(float4*)(hr + lane * 4);
    float4 h1 = *(float4*)(hr + 256 + lane * 4);

    h0.x += fmaxf(d0x * rs * g0.x + b0.x, 0.0f);
    h0.y += fmaxf(d0y * rs * g0.y + b0.y, 0.0f);
    h0.z += fmaxf(d0z * rs * g0.z + b0.z, 0.0f);
    h0.w += fmaxf(d0w * rs * g0.w + b0.w, 0.0f);
    h1.x += fmaxf(d1x * rs * g1.x + b1.x, 0.0f);
    h1.y += fmaxf(d1y * rs * g1.y + b1.y, 0.0f);
    h1.z += fmaxf(d1z * rs * g1.z + b1.z, 0.0f);
    h1.w += fmaxf(d1w * rs * g1.w + b1.w, 0.0f);

    *(float4*)(hr + lane * 4) = h0;
    *(float4*)(hr + 256 + lane * 4) = h1;
}

// ---------------------------------------------------------------------------
// Codebook split (coalesced) + se
// ---------------------------------------------------------------------------
__global__ __launch_bounds__(256) void k_esplit_fast(const float* __restrict__ emb,
                                                     __bf16* __restrict__ Ehi,
                                                     __bf16* __restrict__ Emid,
                                                     __bf16* __restrict__ Elo) {
    const int wv = threadIdx.x >> 6, lane = threadIdx.x & 63;
    const int c = blockIdx.x * 4 + wv;
    float v = emb[(size_t)c * 64 + lane];
    __bf16 h, m, l;
    split3(v, h, m, l);
    Ehi[(size_t)c * 64 + lane] = h;
    Emid[(size_t)c * 64 + lane] = m;
    Elo[(size_t)c * 64 + lane] = l;
}

__global__ void k_esq(const float* __restrict__ emb, float* __restrict__ se) {
    int t = blockIdx.x * 256 + threadIdx.x;
    if (t < NE_) {
        float s = 0.0f;
        for (int k = 0; k < 64; ++k) {
            float v = emb[(size_t)t * 64 + k];
            s += v * v;
        }
        se[t] = s;
    }
}

// ---------------------------------------------------------------------------
// sz[row] = sum(z[row]^2)
// ---------------------------------------------------------------------------
__global__ __launch_bounds__(256) void k_rowsq(const float* __restrict__ z,
                                               float* __restrict__ sz) {
    const int tid = threadIdx.x;
    const int row = blockIdx.x * 64 + (tid >> 2);
    const int part = tid & 3;
    const float4* zp = (const float4*)(z + (size_t)row * 64) + part * 4;
    float s = 0.0f;
#pragma unroll
    for (int i = 0; i < 4; ++i) {
        float4 v = zp[i];
        s += v.x * v.x + v.y * v.y + v.z * v.z + v.w * v.w;
    }
    s += __shfl_xor(s, 1);
    s += __shfl_xor(s, 2);
    if (part == 0) sz[row] = s;
}

// ---------------------------------------------------------------------------
// MFMA distance + argmin: R7 dataflow (24KB dbuf, 32-col chunks) +
// (a) se preloaded to LDS (the in-loop global se load forced a vmcnt(0)
//     drain mid-compute, killing the prefetch every chunk),
// (b) counted-vmcnt double-buffer (m201 two-barrier protocol):
//     barrier#1 (WAR) -> issue stage(ch+1) -> s_waitcnt vmcnt(3)
//     (= wait only for stage(ch), issued a full phase ago) -> barrier#2
//     (propagates all waves' stage completion) -> compute.
// Scheduling-only change: values/order/comparisons identical -> bit-exact.
// ---------------------------------------------------------------------------
__global__ __launch_bounds__(256) void k_distm(const float* __restrict__ z,
                                               const float* __restrict__ se,
                                               const float* __restrict__ sz,
                                               const __bf16* __restrict__ Ehi,
                                               const __bf16* __restrict__ Emid,
                                               const __bf16* __restrict__ Elo,
                                               int* __restrict__ idxw,
                                               float* __restrict__ idxf,
                                               float* __restrict__ lossacc,
                                               int* __restrict__ counts) {
    __shared__ __bf16 eS[2][3][32 * 64];   // 24 KB
    __shared__ float seS[2048];            // 8 KB (se in LDS: out of vmcnt domain)

    const int tid = threadIdx.x;
    const int w = tid >> 6, lane = tid & 63;
    const int r0 = blockIdx.x * 128 + w * 32;
    const int lrow = lane & 31;
    const int half = lane >> 5;

    // staging: 256 threads x 16B = one 32x64 bf16 plane (4KB) per gload
    const int cc = tid >> 3, qq = tid & 7;
    const int off = cc * 64 + (qq ^ (cc & 7)) * 8;
    const int ld = w * 512;

    // preload se -> LDS (coalesced; 8 floats/thread)
#pragma unroll
    for (int i = 0; i < 8; ++i) seS[tid + i * 256] = se[tid + i * 256];

    // persistent A fragments (3-way split of z rows)
    bf16x8 ah[4], am[4], al[4];
    {
        const float* zr = z + (size_t)(r0 + lrow) * 64 + half * 8;
#pragma unroll
        for (int kc = 0; kc < 4; ++kc) {
            float4 u0 = *(const float4*)(zr + kc * 16);
            float4 u1 = *(const float4*)(zr + kc * 16 + 4);
            float v[8] = {u0.x, u0.y, u0.z, u0.w, u1.x, u1.y, u1.z, u1.w};
#pragma unroll
            for (int j = 0; j < 8; ++j) {
                __bf16 hh, mm, ll;
                split3(v[j], hh, mm, ll);
                ah[kc][j] = hh; am[kc][j] = mm; al[kc][j] = ll;
            }
        }
    }

    float szv[16];
#pragma unroll
    for (int r = 0; r < 16; ++r) {
        int rl = (r & 3) + 8 * (r >> 2) + 4 * half;
        szv[r] = sz[r0 + rl];
    }

    float bd[16];
    int bi[16];
#pragma unroll
    for (int r = 0; r < 16; ++r) { bd[r] = 1e30f; bi[r] = 0; }

    __syncthreads();   // seS visible (one-time full drain; all VMEM retired)

    // prologue: stage chunk 0 into buffer 0 (stays in flight into the loop)
    gload_lds16(Ehi + off, &eS[0][0][ld]);
    gload_lds16(Emid + off, &eS[0][1][ld]);
    gload_lds16(Elo + off, &eS[0][2][ld]);

    for (int ch = 0; ch < 64; ++ch) {
        const int cur = ch & 1;
        __builtin_amdgcn_s_barrier();   // #1: all waves done reading eS[cur^1]

        if (ch + 1 < 64) {
            const int nxt = cur ^ 1;
            const int b = (ch + 1) * 2048;
            gload_lds16(Ehi + b + off, &eS[nxt][0][ld]);
            gload_lds16(Emid + b + off, &eS[nxt][1][ld]);
            gload_lds16(Elo + b + off, &eS[nxt][2][ld]);
        }

        // wait only for stage(ch) (3 ops older than the 3 just issued)
        if (ch < 63) asm volatile("s_waitcnt vmcnt(3)" ::: "memory");
        else         asm volatile("s_waitcnt vmcnt(0)" ::: "memory");
        __builtin_amdgcn_sched_barrier(0);
        __builtin_amdgcn_s_barrier();   // #2: every wave's stage(ch) landed

        f32x16 acc;
#pragma unroll
        for (int i = 0; i < 16; ++i) acc[i] = 0.0f;

#pragma unroll
        for (int kc = 0; kc < 4; ++kc) {
            const int q = kc * 2 + half;
            const int g = (q ^ (lrow & 7)) * 8;
            bf16x8 bh = *(const bf16x8*)(&eS[cur][0][lrow * 64 + g]);
            bf16x8 bm = *(const bf16x8*)(&eS[cur][1][lrow * 64 + g]);
            bf16x8 bl = *(const bf16x8*)(&eS[cur][2][lrow * 64 + g]);

            acc = __builtin_amdgcn_mfma_f32_32x32x16_bf16(ah[kc], bh, acc, 0, 0, 0);
            acc = __builtin_amdgcn_mfma_f32_32x32x16_bf16(ah[kc], bm, acc, 0, 0, 0);
            acc = __builtin_amdgcn_mfma_f32_32x32x16_bf16(am[kc], bh, acc, 0, 0, 0);
            acc = __builtin_amdgcn_mfma_f32_32x32x16_bf16(ah[kc], bl, acc, 0, 0, 0);
            acc = __builtin_amdgcn_mfma_f32_32x32x16_bf16(am[kc], bm, acc, 0, 0, 0);
            acc = __builtin_amdgcn_mfma_f32_32x32x16_bf16(al[kc], bh, acc, 0, 0, 0);
        }

        const int c0 = ch * 32;
        const float se0 = seS[c0 + lrow];
        const int   ci0 = c0 + lrow;
#pragma unroll
        for (int r = 0; r < 16; ++r) {
            float d0 = fmaf(-2.0f, acc[r], szv[r] + se0);
            if (d0 < bd[r]) { bd[r] = d0; bi[r] = ci0; }
        }
    }

    // cross-lane argmin within each 32-lane half (lexicographic: d, then idx)
#pragma unroll
    for (int r = 0; r < 16; ++r) {
        float d = bd[r];
        int i = bi[r];
#pragma unroll
        for (int off2 = 1; off2 < 32; off2 <<= 1) {
            float od = __shfl_xor(d, off2);
            int oi = __shfl_xor(i, off2);
            if (od < d || (od == d && oi < i)) { d = od; i = oi; }
        }
        bd[r] = d; bi[r] = i;
    }

    if (lrow == 0) {
        float lsum = 0.0f;
#pragma unroll
        for (int r = 0; r < 16; ++r) {
            int rl = (r & 3) + 8 * (r >> 2) + 4 * half;
            int row = r0 + rl;
            idxw[row] = bi[r];
            idxf[row] = (float)bi[r];
            lsum += bd[r];
            atomicAdd(&counts[bi[r]], 1);
        }
        atomicAdd(lossacc, lsum);
    }
}

// ---------------------------------------------------------------------------
// loss (from accumulated dmin sum) + perplexity (from counts)
// ---------------------------------------------------------------------------
__global__ __launch_bounds__(256) void k_lossperp(const float* __restrict__ lossacc,
                                                  const int* __restrict__ counts,
                                                  float* __restrict__ out) {
    __shared__ double red[256];
    const int tid = threadIdx.x;

    double hsum = 0.0;
    for (int i = tid; i < NE_; i += 256) {
        float p = (float)counts[i] / 196608.0f;
        float lg = logf(p + 1e-10f);
        hsum += (double)(p * lg);
    }
    red[tid] = hsum;
    __syncthreads();
    for (int off = 128; off > 0; off >>= 1) {
        if (tid < off) red[tid] += red[tid + off];
        __syncthreads();
    }
    if (tid == 0) {
        out[PERP_OFF] = (float)exp(-red[0]);
        out[0] = (float)((double)lossacc[0] * (1.0 + BETA_) / ((double)ROWS_ * IN_));
    }
}

// ---------------------------------------------------------------------------
// per-block pinv least-squares (single-wave workgroup)
// ---------------------------------------------------------------------------
__global__ __launch_bounds__(64) void k_pinv(const float* __restrict__ xin,
                                             const float* __restrict__ emb,
                                             const int* __restrict__ idxw,
                                             float* __restrict__ coeff,
                                             float* __restrict__ xhat) {
    __shared__ float aS[12][65];
    __shared__ float xS[64];
    __shared__ double GS[12][12];
    __shared__ double bS[12];
    __shared__ double yS[12];
    __shared__ double uS[12];
    __shared__ float cS[12];

    const int lane = threadIdx.x;
    const int b = blockIdx.x;

    int my = 0;
    if (lane < 12) my = idxw[(size_t)b * 12 + lane];
    int id[12];
#pragma unroll
    for (int p = 0; p < 12; ++p) id[p] = __shfl(my, p);

    int rep = lane, mcnt = 1;
    if (lane < 12) {
        rep = -1;
        mcnt = 0;
        for (int q = 0; q < 12; ++q) {
            if (id[q] == id[lane]) {
                if (rep < 0) rep = q;
                mcnt++;
            }
        }
    }

#pragma unroll
    for (int p = 0; p < 12; ++p) aS[p][lane] = emb[(size_t)id[p] * 64 + lane];
    xS[lane] = xin[(size_t)b * 64 + lane];
    __syncthreads();

    for (int item = lane; item < 90; item += 64) {
        if (item < 78) {
            int j = 0, k = 0, c = item;
            for (j = 0; j < 12; ++j) {
                int cnt = 12 - j;
                if (c < cnt) { k = j + c; break; }
                c -= cnt;
            }
            double s = 0.0;
            for (int t = 0; t < 64; ++t) s += (double)aS[j][t] * (double)aS[k][t];
            GS[j][k] = s;
            GS[k][j] = s;
        } else {
            int j = item - 78;
            double s = 0.0;
            for (int t = 0; t < 64; ++t) s += (double)aS[j][t] * (double)xS[t];
            bS[j] = s;
        }
    }
    __syncthreads();

    if (lane == 0) {
        for (int p = 0; p < 12; ++p) {
            int rp = -1;
            for (int q = 0; q < 12; ++q) {
                if (id[q] == id[p]) { rp = q; break; }
            }
            if (rp != p) {
                for (int q = 0; q < 12; ++q) {
                    GS[p][q] = 0.0;
                    GS[q][p] = 0.0;
                }
                GS[p][p] = 1.0;
                bS[p] = 0.0;
            }
        }
    }
    __syncthreads();

    for (int j = 0; j < 12; ++j) {
        if (lane == j) {
            double s = GS[j][j];
            for (int k = 0; k < j; ++k) {
                double l = GS[j][k];
                s -= l * l;
            }
            GS[j][j] = sqrt(fmax(s, 1e-30));
        }
        __syncthreads();
        if (lane > j && lane < 12) {
            double s = GS[lane][j];
            for (int k = 0; k < j; ++k) s -= GS[lane][k] * GS[j][k];
            GS[lane][j] = s / GS[j][j];
        }
        __syncthreads();
    }

    double s = (lane < 12) ? bS[lane] : 0.0;
    for (int k = 0; k < 12; ++k) {
        if (lane == k) yS[k] = s / GS[k][k];
        __syncthreads();
        double yk = yS[k];
        if (lane > k && lane < 12) s -= GS[lane][k] * yk;
    }
    double tacc = 0.0;
    for (int k = 11; k >= 0; --k) {
        if (lane == k) uS[k] = (yS[k] - tacc) / GS[k][k];
        __syncthreads();
        double uk = uS[k];
        if (lane < k) tacc += GS[k][lane] * uk;
    }
    __syncthreads();

    if (lane < 12) {
        double c = uS[rep] / (double)mcnt;
        coeff[(size_t)b * 12 + lane] = (float)c;
        cS[lane] = (float)c;
    }
    __syncthreads();

    float sx = 0.0f;
#pragma unroll
    for (int p = 0; p < 12; ++p) sx += aS[p][lane] * cS[p];
    xhat[(size_t)b * 64 + lane] = sx;
}

// ---------------------------------------------------------------------------

extern "C" void kernel_launch(void* const* d_in, const int* in_sizes, int n_in,
                              void* d_out, int out_size, void* d_ws, size_t ws_size,
                              hipStream_t stream) {
    const float* x        = (const float*)d_in[0];
    const float* enc_w1   = (const float*)d_in[1];
    const float* enc_b1   = (const float*)d_in[2];
    const float* res_w    = (const float*)d_in[3];
    const float* res_b    = (const float*)d_in[4];
    const float* res_g    = (const float*)d_in[5];
    const float* res_beta = (const float*)d_in[6];
    const float* enc_w2   = (const float*)d_in[7];
    const float* enc_b2   = (const float*)d_in[8];
    const float* emb      = (const float*)d_in[9];

    float* out = (float*)d_out;

    // workspace layout
    float* h  = (float*)d_ws;            // B*512 f32 (32MB), reused after enc2
    float* tz = h + (size_t)B_ * DENC_;  // B*768 f32 (48MB): t then z
    // VQ scratch overlapping h (dead after enc2):
    float* se    = h;                                        // 2048
    float* sz    = h + 2048;                                 // ROWS_
    int*   idxw  = (int*)(h + 2048 + (size_t)ROWS_);         // ROWS_
    int*   cnts  = (int*)(h + 2048 + 2 * (size_t)ROWS_);     // 2048
    float* lossacc = (float*)(cnts + NE_);                   // 1 (+pad)
    __bf16* Ehi  = (__bf16*)(h + 2048 + 2 * (size_t)ROWS_ + 2048 + 16);
    __bf16* Emid = Ehi + (size_t)NE_ * 64;
    __bf16* Elo  = Emid + (size_t)NE_ * 64;
    // pre-split weight planes (transposed [N][K]) after tz:
    __bf16* W1h = (__bf16*)(tz + (size_t)B_ * 768);   // 512*64 each
    __bf16* W1m = W1h + (size_t)DENC_ * IN_;
    __bf16* W1l = W1m + (size_t)DENC_ * IN_;
    __bf16* Wrh = W1l + (size_t)DENC_ * IN_;          // 512*512 each
    __bf16* Wrm = Wrh + (size_t)DENC_ * DENC_;
    __bf16* Wrl = Wrm + (size_t)DENC_ * DENC_;
    __bf16* W2h = Wrl + (size_t)DENC_ * DENC_;        // 768*512 each
    __bf16* W2m = W2h + (size_t)768 * DENC_;
    __bf16* W2l = W2m + (size_t)768 * DENC_;

    float* t = tz;
    float* z = tz;

    // pre-split weights (transposed bf16 planes)
    k_wsplit<<<(DENC_ * IN_ + 255) / 256, 256, 0, stream>>>(enc_w1, W1h, W1m, W1l, 6, DENC_, DENC_ * IN_);
    k_wsplit<<<(DENC_ * DENC_ + 255) / 256, 256, 0, stream>>>(res_w, Wrh, Wrm, Wrl, 9, DENC_, DENC_ * DENC_);
    k_wsplit<<<(768 * DENC_ + 255) / 256, 256, 0, stream>>>(enc_w2, W2h, W2m, W2l, 9, 768, 768 * DENC_);

    // encoder (MFMA path, 256-row blocks, double-buffered, XCD-swizzled)
    k_gemm_mfma<<<dim3(DENC_ / 64, B_ / 256), 256, 0, stream>>>(x, W1h, W1m, W1l, enc_b1, h, DENC_, IN_);
    for (int r = 0; r < 2; ++r) {
        k_gemm_mfma<<<dim3(DENC_ / 64, B_ / 256), 256, 0, stream>>>(h, Wrh, Wrm, Wrl, res_b, t, DENC_, DENC_);
        k_lnrelu<<<B_ / 4, 256, 0, stream>>>(t, h, res_g, res_beta);
    }
    k_gemm_mfma<<<dim3(768 / 64, B_ / 256), 256, 0, stream>>>(h, W2h, W2m, W2l, enc_b2, z, 768, DENC_);

    // VQ
    hipMemsetAsync(cnts, 0, (NE_ + 16) * sizeof(int), stream);
    k_esplit_fast<<<NE_ / 4, 256, 0, stream>>>(emb, Ehi, Emid, Elo);
    k_esq<<<NE_ / 256, 256, 0, stream>>>(emb, se);
    k_rowsq<<<ROWS_ / 64, 256, 0, stream>>>(z, sz);
    k_distm<<<ROWS_ / 128, 256, 0, stream>>>(z, se, sz, Ehi, Emid, Elo,
                                             idxw, out + IDXF_OFF, lossacc, cnts);
    k_lossperp<<<1, 256, 0, stream>>>(lossacc, cnts, out);
    k_pinv<<<B_, 64, 0, stream>>>(x, emb, idxw, out + COEF_OFF, out + XHAT_OFF);
}

// Round 12
// 694.414 us; speedup vs baseline: 1.1684x; 1.0392x over previous
//
#include <hip/hip_runtime.h>
#include <math.h>

#define B_    16384
#define IN_   64
#define DENC_ 512
#define NE_   2048
#define P_    12
#define ROWS_ 196608      // B_*P_
#define BETA_ 0.25

// output layout (all float32, concatenated in return order)
#define XHAT_OFF 1
#define PERP_OFF 1048577   // 1 + 16384*64
#define IDXF_OFF 1048578
#define COEF_OFF 1245186   // IDXF_OFF + 196608

typedef __bf16 bf16x8 __attribute__((ext_vector_type(8)));
typedef float  f32x16 __attribute__((ext_vector_type(16)));

__device__ __forceinline__ void split3(float v, __bf16& h, __bf16& m, __bf16& l) {
    h = (__bf16)v;
    float r1 = v - (float)h;
    m = (__bf16)r1;
    float r2 = r1 - (float)m;
    l = (__bf16)r2;
}

// async global->LDS 16B per lane; dest = wave-uniform base + lane*16
__device__ __forceinline__ void gload_lds16(const void* g, void* l) {
    __builtin_amdgcn_global_load_lds((const __attribute__((address_space(1))) void*)g,
                                     (__attribute__((address_space(3))) void*)l, 16, 0, 0);
}

// ---------------------------------------------------------------------------
// Fused pre-split of all three weights (one launch). W planes live after tz
// (no overlap with h) -> safe to run up front.
// ---------------------------------------------------------------------------
#define WS_S1 32768     // 512*64
#define WS_S2 294912    // + 512*512
#define WS_S3 688128    // + 768*512
__global__ __launch_bounds__(256) void k_wsplit_all(const float* __restrict__ enc_w1,
                                                    const float* __restrict__ res_w,
                                                    const float* __restrict__ enc_w2,
                                                    __bf16* __restrict__ W1h, __bf16* __restrict__ W1m, __bf16* __restrict__ W1l,
                                                    __bf16* __restrict__ Wrh, __bf16* __restrict__ Wrm, __bf16* __restrict__ Wrl,
                                                    __bf16* __restrict__ W2h, __bf16* __restrict__ W2m, __bf16* __restrict__ W2l) {
    int idx = blockIdx.x * 256 + threadIdx.x;
    if (idx >= WS_S3) return;
    float v;
    __bf16* dh; __bf16* dm; __bf16* dl;
    int o;
    if (idx < WS_S1) {
        o = idx;
        int n = o >> 6, k = o & 63;
        v = enc_w1[(size_t)k * DENC_ + n];
        dh = W1h; dm = W1m; dl = W1l;
    } else if (idx < WS_S2) {
        o = idx - WS_S1;
        int n = o >> 9, k = o & 511;
        v = res_w[(size_t)k * DENC_ + n];
        dh = Wrh; dm = Wrm; dl = Wrl;
    } else {
        o = idx - WS_S2;
        int n = o >> 9, k = o & 511;
        v = enc_w2[(size_t)k * 768 + n];
        dh = W2h; dm = W2m; dl = W2l;
    }
    __bf16 h, m, l;
    split3(v, h, m, l);
    dh[o] = h; dm[o] = m; dl[o] = l;
}

// ---------------------------------------------------------------------------
// MFMA GEMM + bias (bf16 3-term split, exact baseline term order per acc),
// 64 rows/wave (2 rowblocks), block = 256 rows x 64 cols. Double-buffered
// LDS + global_load_lds staging. XCD-aware block swizzle (R6: ~-45us).
// R7-verbatim (known-good). Bit-identical C.
// ---------------------------------------------------------------------------
__global__ __launch_bounds__(256, 2) void k_gemm_mfma(const float* __restrict__ A,
                                                      const __bf16* __restrict__ Bh,
                                                      const __bf16* __restrict__ Bm,
                                                      const __bf16* __restrict__ Bl,
                                                      const float* __restrict__ bias,
                                                      float* __restrict__ C,
                                                      int N, int K) {
    __shared__ __bf16 eS[2][3][64 * 64];   // 48 KB

    // XCD swizzle (bijective: all grids here have nwg % 8 == 0).
    const int nwg  = gridDim.x * gridDim.y;
    const int flat = blockIdx.y * gridDim.x + blockIdx.x;
    const int nf   = (flat & 7) * (nwg >> 3) + (flat >> 3);
    const int bx   = nf % gridDim.x;
    const int by   = nf / gridDim.x;

    const int tid = threadIdx.x;
    const int w = tid >> 6, lane = tid & 63;
    const int r0 = by * 256 + w * 64;
    const int n0 = bx * 64;
    const int lrow = lane & 31;
    const int half = lane >> 5;

    const int cc0 = tid >> 3, qq = tid & 7;
    const int cc1 = cc0 + 32;
    const size_t off0 = (size_t)cc0 * K + (size_t)((qq ^ (cc0 & 7)) * 8);
    const size_t off1 = (size_t)cc1 * K + (size_t)((qq ^ (cc1 & 7)) * 8);
    const size_t nbase = (size_t)n0 * K;
    const int ld0 = w * 512;
    const int ld1 = 2048 + w * 512;

    f32x16 acc00, acc01, acc10, acc11;
#pragma unroll
    for (int i = 0; i < 16; ++i) { acc00[i] = 0.0f; acc01[i] = 0.0f; acc10[i] = 0.0f; acc11[i] = 0.0f; }

    {
        const size_t b = nbase;
        gload_lds16(Bh + b + off0, &eS[0][0][ld0]);
        gload_lds16(Bh + b + off1, &eS[0][0][ld1]);
        gload_lds16(Bm + b + off0, &eS[0][1][ld0]);
        gload_lds16(Bm + b + off1, &eS[0][1][ld1]);
        gload_lds16(Bl + b + off0, &eS[0][2][ld0]);
        gload_lds16(Bl + b + off1, &eS[0][2][ld1]);
    }

    const int nch = K >> 6;
    for (int ch = 0; ch < nch; ++ch) {
        const int cur = ch & 1;
        __syncthreads();

        if (ch + 1 < nch) {
            const int nxt = cur ^ 1;
            const size_t b = nbase + (size_t)(ch + 1) * 64;
            gload_lds16(Bh + b + off0, &eS[nxt][0][ld0]);
            gload_lds16(Bh + b + off1, &eS[nxt][0][ld1]);
            gload_lds16(Bm + b + off0, &eS[nxt][1][ld0]);
            gload_lds16(Bm + b + off1, &eS[nxt][1][ld1]);
            gload_lds16(Bl + b + off0, &eS[nxt][2][ld0]);
            gload_lds16(Bl + b + off1, &eS[nxt][2][ld1]);
        }

        bf16x8 ah0[4], am0[4], al0[4], ah1[4], am1[4], al1[4];
        {
            const float* ar0 = A + (size_t)(r0 + lrow) * K + ch * 64 + half * 8;
            const float* ar1 = ar0 + (size_t)32 * K;
#pragma unroll
            for (int kc = 0; kc < 4; ++kc) {
                float4 u0 = *(const float4*)(ar0 + kc * 16);
                float4 u1 = *(const float4*)(ar0 + kc * 16 + 4);
                float va[8] = {u0.x, u0.y, u0.z, u0.w, u1.x, u1.y, u1.z, u1.w};
                float4 t0 = *(const float4*)(ar1 + kc * 16);
                float4 t1 = *(const float4*)(ar1 + kc * 16 + 4);
                float vb[8] = {t0.x, t0.y, t0.z, t0.w, t1.x, t1.y, t1.z, t1.w};
#pragma unroll
                for (int j = 0; j < 8; ++j) {
                    __bf16 hh, mm, ll;
                    split3(va[j], hh, mm, ll);
                    ah0[kc][j] = hh; am0[kc][j] = mm; al0[kc][j] = ll;
                    split3(vb[j], hh, mm, ll);
                    ah1[kc][j] = hh; am1[kc][j] = mm; al1[kc][j] = ll;
                }
            }
        }

#pragma unroll
        for (int kc = 0; kc < 4; ++kc) {
            const int q = kc * 2 + half;
            const int g = (q ^ (lrow & 7)) * 8;
            bf16x8 b0h = *(const bf16x8*)(&eS[cur][0][lrow * 64 + g]);
            bf16x8 b0m = *(const bf16x8*)(&eS[cur][1][lrow * 64 + g]);
            bf16x8 b0l = *(const bf16x8*)(&eS[cur][2][lrow * 64 + g]);
            bf16x8 b1h = *(const bf16x8*)(&eS[cur][0][(lrow + 32) * 64 + g]);
            bf16x8 b1m = *(const bf16x8*)(&eS[cur][1][(lrow + 32) * 64 + g]);
            bf16x8 b1l = *(const bf16x8*)(&eS[cur][2][(lrow + 32) * 64 + g]);

            acc00 = __builtin_amdgcn_mfma_f32_32x32x16_bf16(ah0[kc], b0h, acc00, 0, 0, 0);
            acc01 = __builtin_amdgcn_mfma_f32_32x32x16_bf16(ah0[kc], b1h, acc01, 0, 0, 0);
            acc10 = __builtin_amdgcn_mfma_f32_32x32x16_bf16(ah1[kc], b0h, acc10, 0, 0, 0);
            acc11 = __builtin_amdgcn_mfma_f32_32x32x16_bf16(ah1[kc], b1h, acc11, 0, 0, 0);
            acc00 = __builtin_amdgcn_mfma_f32_32x32x16_bf16(ah0[kc], b0m, acc00, 0, 0, 0);
            acc01 = __builtin_amdgcn_mfma_f32_32x32x16_bf16(ah0[kc], b1m, acc01, 0, 0, 0);
            acc10 = __builtin_amdgcn_mfma_f32_32x32x16_bf16(ah1[kc], b0m, acc10, 0, 0, 0);
            acc11 = __builtin_amdgcn_mfma_f32_32x32x16_bf16(ah1[kc], b1m, acc11, 0, 0, 0);
            acc00 = __builtin_amdgcn_mfma_f32_32x32x16_bf16(am0[kc], b0h, acc00, 0, 0, 0);
            acc01 = __builtin_amdgcn_mfma_f32_32x32x16_bf16(am0[kc], b1h, acc01, 0, 0, 0);
            acc10 = __builtin_amdgcn_mfma_f32_32x32x16_bf16(am1[kc], b0h, acc10, 0, 0, 0);
            acc11 = __builtin_amdgcn_mfma_f32_32x32x16_bf16(am1[kc], b1h, acc11, 0, 0, 0);
            acc00 = __builtin_amdgcn_mfma_f32_32x32x16_bf16(ah0[kc], b0l, acc00, 0, 0, 0);
            acc01 = __builtin_amdgcn_mfma_f32_32x32x16_bf16(ah0[kc], b1l, acc01, 0, 0, 0);
            acc10 = __builtin_amdgcn_mfma_f32_32x32x16_bf16(ah1[kc], b0l, acc10, 0, 0, 0);
            acc11 = __builtin_amdgcn_mfma_f32_32x32x16_bf16(ah1[kc], b1l, acc11, 0, 0, 0);
            acc00 = __builtin_amdgcn_mfma_f32_32x32x16_bf16(am0[kc], b0m, acc00, 0, 0, 0);
            acc01 = __builtin_amdgcn_mfma_f32_32x32x16_bf16(am0[kc], b1m, acc01, 0, 0, 0);
            acc10 = __builtin_amdgcn_mfma_f32_32x32x16_bf16(am1[kc], b0m, acc10, 0, 0, 0);
            acc11 = __builtin_amdgcn_mfma_f32_32x32x16_bf16(am1[kc], b1m, acc11, 0, 0, 0);
            acc00 = __builtin_amdgcn_mfma_f32_32x32x16_bf16(al0[kc], b0h, acc00, 0, 0, 0);
            acc01 = __builtin_amdgcn_mfma_f32_32x32x16_bf16(al0[kc], b1h, acc01, 0, 0, 0);
            acc10 = __builtin_amdgcn_mfma_f32_32x32x16_bf16(al1[kc], b0h, acc10, 0, 0, 0);
            acc11 = __builtin_amdgcn_mfma_f32_32x32x16_bf16(al1[kc], b1h, acc11, 0, 0, 0);
        }
    }

    const int col0 = n0 + lrow, col1 = col0 + 32;
    const float bv0 = bias[col0], bv1 = bias[col1];
#pragma unroll
    for (int r = 0; r < 16; ++r) {
        int rr = (r & 3) + 8 * (r >> 2) + 4 * half;
        C[(size_t)(r0 + rr) * N + col0] = acc00[r] + bv0;
        C[(size_t)(r0 + rr) * N + col1] = acc01[r] + bv1;
        C[(size_t)(r0 + 32 + rr) * N + col0] = acc10[r] + bv0;
        C[(size_t)(r0 + 32 + rr) * N + col1] = acc11[r] + bv1;
    }
}

// ---------------------------------------------------------------------------
// h = h + relu(layer_norm(t) * g + beta)
// ---------------------------------------------------------------------------
__global__ __launch_bounds__(256) void k_lnrelu(const float* __restrict__ t,
                                                float* __restrict__ h,
                                                const float* __restrict__ g,
                                                const float* __restrict__ beta) {
    const int tid = threadIdx.x;
    const int wv = tid >> 6, lane = tid & 63;
    const int row = blockIdx.x * 4 + wv;
    const float* tr = t + (size_t)row * DENC_;
    float* hr = h + (size_t)row * DENC_;

    float4 v0 = *(const float4*)(tr + lane * 4);
    float4 v1 = *(const float4*)(tr + 256 + lane * 4);

    float s = v0.x + v0.y + v0.z + v0.w + v1.x + v1.y + v1.z + v1.w;
#pragma unroll
    for (int m = 1; m < 64; m <<= 1) s += __shfl_xor(s, m);
    float mu = s / 512.0f;

    float d0x = v0.x - mu, d0y = v0.y - mu, d0z = v0.z - mu, d0w = v0.w - mu;
    float d1x = v1.x - mu, d1y = v1.y - mu, d1z = v1.z - mu, d1w = v1.w - mu;
    float vs = d0x * d0x + d0y * d0y + d0z * d0z + d0w * d0w +
               d1x * d1x + d1y * d1y + d1z * d1z + d1w * d1w;
#pragma unroll
    for (int m = 1; m < 64; m <<= 1) vs += __shfl_xor(vs, m);
    float var = vs / 512.0f;
    float rs = (float)(1.0 / sqrt((double)var + 1e-5));

    float4 g0 = *(const float4*)(g + lane * 4);
    float4 g1 = *(const float4*)(g + 256 + lane * 4);
    float4 b0 = *(const float4*)(beta + lane * 4);
    float4 b1 = *(const float4*)(beta + 256 + lane * 4);

    float4 h0 = *(float4*)(hr + lane * 4);
    float4 h1 = *(float4*)(hr + 256 + lane * 4);

    h0.x += fmaxf(d0x * rs * g0.x + b0.x, 0.0f);
    h0.y += fmaxf(d0y * rs * g0.y + b0.y, 0.0f);
    h0.z += fmaxf(d0z * rs * g0.z + b0.z, 0.0f);
    h0.w += fmaxf(d0w * rs * g0.w + b0.w, 0.0f);
    h1.x += fmaxf(d1x * rs * g1.x + b1.x, 0.0f);
    h1.y += fmaxf(d1y * rs * g1.y + b1.y, 0.0f);
    h1.z += fmaxf(d1z * rs * g1.z + b1.z, 0.0f);
    h1.w += fmaxf(d1w * rs * g1.w + b1.w, 0.0f);

    *(float4*)(hr + lane * 4) = h0;
    *(float4*)(hr + 256 + lane * 4) = h1;
}

// ---------------------------------------------------------------------------
// Fused: codebook split (blocks 0..511), esq + cnts/lossacc zero (blocks
// 512..519). MUST run AFTER enc2 (outputs overlap h). esq keeps the exact
// per-thread serial sum -> se bit-identical.
// ---------------------------------------------------------------------------
__global__ __launch_bounds__(256) void k_eprep(const float* __restrict__ emb,
                                               __bf16* __restrict__ Ehi,
                                               __bf16* __restrict__ Emid,
                                               __bf16* __restrict__ Elo,
                                               float* __restrict__ se,
                                               int* __restrict__ cnts,
                                               float* __restrict__ lossacc) {
    if (blockIdx.x < NE_ / 4) {
        const int wv = threadIdx.x >> 6, lane = threadIdx.x & 63;
        const int c = blockIdx.x * 4 + wv;
        float v = emb[(size_t)c * 64 + lane];
        __bf16 h, m, l;
        split3(v, h, m, l);
        Ehi[(size_t)c * 64 + lane] = h;
        Emid[(size_t)c * 64 + lane] = m;
        Elo[(size_t)c * 64 + lane] = l;
    } else {
        int t = (blockIdx.x - NE_ / 4) * 256 + threadIdx.x;
        if (t < NE_) {
            float s = 0.0f;
            for (int k = 0; k < 64; ++k) {
                float v = emb[(size_t)t * 64 + k];
                s += v * v;
            }
            se[t] = s;
            cnts[t] = 0;
            if (t == 0) lossacc[0] = 0.0f;
        }
    }
}

// ---------------------------------------------------------------------------
// sz[row] = sum(z[row]^2)
// ---------------------------------------------------------------------------
__global__ __launch_bounds__(256) void k_rowsq(const float* __restrict__ z,
                                               float* __restrict__ sz) {
    const int tid = threadIdx.x;
    const int row = blockIdx.x * 64 + (tid >> 2);
    const int part = tid & 3;
    const float4* zp = (const float4*)(z + (size_t)row * 64) + part * 4;
    float s = 0.0f;
#pragma unroll
    for (int i = 0; i < 4; ++i) {
        float4 v = zp[i];
        s += v.x * v.x + v.y * v.y + v.z * v.z + v.w * v.w;
    }
    s += __shfl_xor(s, 1);
    s += __shfl_xor(s, 2);
    if (part == 0) sz[row] = s;
}

// ---------------------------------------------------------------------------
// MFMA distance + argmin: R7 structure (24KB dbuf, 32-col chunks, simple
// __syncthreads loop) + zero-C first MFMA per chunk (bit-exact: C operand
// value is 0.0 either way; saves 16 acc-init v_movs per chunk).
// ---------------------------------------------------------------------------
__global__ __launch_bounds__(256) void k_distm(const float* __restrict__ z,
                                               const float* __restrict__ se,
                                               const float* __restrict__ sz,
                                               const __bf16* __restrict__ Ehi,
                                               const __bf16* __restrict__ Emid,
                                               const __bf16* __restrict__ Elo,
                                               int* __restrict__ idxw,
                                               float* __restrict__ idxf,
                                               float* __restrict__ lossacc,
                                               int* __restrict__ counts) {
    __shared__ __bf16 eS[2][3][32 * 64];   // 24 KB

    const int tid = threadIdx.x;
    const int w = tid >> 6, lane = tid & 63;
    const int r0 = blockIdx.x * 128 + w * 32;
    const int lrow = lane & 31;
    const int half = lane >> 5;

    // staging: 256 threads x 16B = one 32x64 bf16 plane (4KB) per gload
    const int cc = tid >> 3, qq = tid & 7;
    const int off = cc * 64 + (qq ^ (cc & 7)) * 8;
    const int ld = w * 512;

    // persistent A fragments (3-way split of z rows)
    bf16x8 ah[4], am[4], al[4];
    {
        const float* zr = z + (size_t)(r0 + lrow) * 64 + half * 8;
#pragma unroll
        for (int kc = 0; kc < 4; ++kc) {
            float4 u0 = *(const float4*)(zr + kc * 16);
            float4 u1 = *(const float4*)(zr + kc * 16 + 4);
            float v[8] = {u0.x, u0.y, u0.z, u0.w, u1.x, u1.y, u1.z, u1.w};
#pragma unroll
            for (int j = 0; j < 8; ++j) {
                __bf16 hh, mm, ll;
                split3(v[j], hh, mm, ll);
                ah[kc][j] = hh; am[kc][j] = mm; al[kc][j] = ll;
            }
        }
    }

    float szv[16];
#pragma unroll
    for (int r = 0; r < 16; ++r) {
        int rl = (r & 3) + 8 * (r >> 2) + 4 * half;
        szv[r] = sz[r0 + rl];
    }

    float bd[16];
    int bi[16];
#pragma unroll
    for (int r = 0; r < 16; ++r) { bd[r] = 1e30f; bi[r] = 0; }

    // loop-invariant zero accumulator (C of each chunk's first MFMA)
    f32x16 zacc;
#pragma unroll
    for (int i = 0; i < 16; ++i) zacc[i] = 0.0f;

    // prologue: stage chunk 0 into buffer 0
    gload_lds16(Ehi + off, &eS[0][0][ld]);
    gload_lds16(Emid + off, &eS[0][1][ld]);
    gload_lds16(Elo + off, &eS[0][2][ld]);

    for (int ch = 0; ch < 64; ++ch) {
        const int cur = ch & 1;
        __syncthreads();   // drains stage(ch); issued a full compute phase ago

        if (ch + 1 < 64) {
            const int nxt = cur ^ 1;
            const int b = (ch + 1) * 2048;
            gload_lds16(Ehi + b + off, &eS[nxt][0][ld]);
            gload_lds16(Emid + b + off, &eS[nxt][1][ld]);
            gload_lds16(Elo + b + off, &eS[nxt][2][ld]);
        }

        f32x16 acc;
        // kc = 0: first term accumulates into the zero vector (bit-exact)
        {
            const int q = half;
            const int g = (q ^ (lrow & 7)) * 8;
            bf16x8 bh = *(const bf16x8*)(&eS[cur][0][lrow * 64 + g]);
            bf16x8 bm = *(const bf16x8*)(&eS[cur][1][lrow * 64 + g]);
            bf16x8 bl = *(const bf16x8*)(&eS[cur][2][lrow * 64 + g]);

            acc = __builtin_amdgcn_mfma_f32_32x32x16_bf16(ah[0], bh, zacc, 0, 0, 0);
            acc = __builtin_amdgcn_mfma_f32_32x32x16_bf16(ah[0], bm, acc, 0, 0, 0);
            acc = __builtin_amdgcn_mfma_f32_32x32x16_bf16(am[0], bh, acc, 0, 0, 0);
            acc = __builtin_amdgcn_mfma_f32_32x32x16_bf16(ah[0], bl, acc, 0, 0, 0);
            acc = __builtin_amdgcn_mfma_f32_32x32x16_bf16(am[0], bm, acc, 0, 0, 0);
            acc = __builtin_amdgcn_mfma_f32_32x32x16_bf16(al[0], bh, acc, 0, 0, 0);
        }
#pragma unroll
        for (int kc = 1; kc < 4; ++kc) {
            const int q = kc * 2 + half;
            const int g = (q ^ (lrow & 7)) * 8;
            bf16x8 bh = *(const bf16x8*)(&eS[cur][0][lrow * 64 + g]);
            bf16x8 bm = *(const bf16x8*)(&eS[cur][1][lrow * 64 + g]);
            bf16x8 bl = *(const bf16x8*)(&eS[cur][2][lrow * 64 + g]);

            acc = __builtin_amdgcn_mfma_f32_32x32x16_bf16(ah[kc], bh, acc, 0, 0, 0);
            acc = __builtin_amdgcn_mfma_f32_32x32x16_bf16(ah[kc], bm, acc, 0, 0, 0);
            acc = __builtin_amdgcn_mfma_f32_32x32x16_bf16(am[kc], bh, acc, 0, 0, 0);
            acc = __builtin_amdgcn_mfma_f32_32x32x16_bf16(ah[kc], bl, acc, 0, 0, 0);
            acc = __builtin_amdgcn_mfma_f32_32x32x16_bf16(am[kc], bm, acc, 0, 0, 0);
            acc = __builtin_amdgcn_mfma_f32_32x32x16_bf16(al[kc], bh, acc, 0, 0, 0);
        }

        const int c0 = ch * 32;
        const float se0 = se[c0 + lrow];
        const int   ci0 = c0 + lrow;
#pragma unroll
        for (int r = 0; r < 16; ++r) {
            float d0 = fmaf(-2.0f, acc[r], szv[r] + se0);
            if (d0 < bd[r]) { bd[r] = d0; bi[r] = ci0; }
        }
    }

    // cross-lane argmin within each 32-lane half (lexicographic: d, then idx)
#pragma unroll
    for (int r = 0; r < 16; ++r) {
        float d = bd[r];
        int i = bi[r];
#pragma unroll
        for (int off2 = 1; off2 < 32; off2 <<= 1) {
            float od = __shfl_xor(d, off2);
            int oi = __shfl_xor(i, off2);
            if (od < d || (od == d && oi < i)) { d = od; i = oi; }
        }
        bd[r] = d; bi[r] = i;
    }

    if (lrow == 0) {
        float lsum = 0.0f;
#pragma unroll
        for (int r = 0; r < 16; ++r) {
            int rl = (r & 3) + 8 * (r >> 2) + 4 * half;
            int row = r0 + rl;
            idxw[row] = bi[r];
            idxf[row] = (float)bi[r];
            lsum += bd[r];
            atomicAdd(&counts[bi[r]], 1);
        }
        atomicAdd(lossacc, lsum);
    }
}

// ---------------------------------------------------------------------------
// loss (from accumulated dmin sum) + perplexity (from counts)
// ---------------------------------------------------------------------------
__global__ __launch_bounds__(256) void k_lossperp(const float* __restrict__ lossacc,
                                                  const int* __restrict__ counts,
                                                  float* __restrict__ out) {
    __shared__ double red[256];
    const int tid = threadIdx.x;

    double hsum = 0.0;
    for (int i = tid; i < NE_; i += 256) {
        float p = (float)counts[i] / 196608.0f;
        float lg = logf(p + 1e-10f);
        hsum += (double)(p * lg);
    }
    red[tid] = hsum;
    __syncthreads();
    for (int off = 128; off > 0; off >>= 1) {
        if (tid < off) red[tid] += red[tid + off];
        __syncthreads();
    }
    if (tid == 0) {
        out[PERP_OFF] = (float)exp(-red[0]);
        out[0] = (float)((double)lossacc[0] * (1.0 + BETA_) / ((double)ROWS_ * IN_));
    }
}

// ---------------------------------------------------------------------------
// per-block pinv least-squares (single-wave workgroup)
// ---------------------------------------------------------------------------
__global__ __launch_bounds__(64) void k_pinv(const float* __restrict__ xin,
                                             const float* __restrict__ emb,
                                             const int* __restrict__ idxw,
                                             float* __restrict__ coeff,
                                             float* __restrict__ xhat) {
    __shared__ float aS[12][65];
    __shared__ float xS[64];
    __shared__ double GS[12][12];
    __shared__ double bS[12];
    __shared__ double yS[12];
    __shared__ double uS[12];
    __shared__ float cS[12];

    const int lane = threadIdx.x;
    const int b = blockIdx.x;

    int my = 0;
    if (lane < 12) my = idxw[(size_t)b * 12 + lane];
    int id[12];
#pragma unroll
    for (int p = 0; p < 12; ++p) id[p] = __shfl(my, p);

    int rep = lane, mcnt = 1;
    if (lane < 12) {
        rep = -1;
        mcnt = 0;
        for (int q = 0; q < 12; ++q) {
            if (id[q] == id[lane]) {
                if (rep < 0) rep = q;
                mcnt++;
            }
        }
    }

#pragma unroll
    for (int p = 0; p < 12; ++p) aS[p][lane] = emb[(size_t)id[p] * 64 + lane];
    xS[lane] = xin[(size_t)b * 64 + lane];
    __syncthreads();

    for (int item = lane; item < 90; item += 64) {
        if (item < 78) {
            int j = 0, k = 0, c = item;
            for (j = 0; j < 12; ++j) {
                int cnt = 12 - j;
                if (c < cnt) { k = j + c; break; }
                c -= cnt;
            }
            double s = 0.0;
            for (int t = 0; t < 64; ++t) s += (double)aS[j][t] * (double)aS[k][t];
            GS[j][k] = s;
            GS[k][j] = s;
        } else {
            int j = item - 78;
            double s = 0.0;
            for (int t = 0; t < 64; ++t) s += (double)aS[j][t] * (double)xS[t];
            bS[j] = s;
        }
    }
    __syncthreads();

    if (lane == 0) {
        for (int p = 0; p < 12; ++p) {
            int rp = -1;
            for (int q = 0; q < 12; ++q) {
                if (id[q] == id[p]) { rp = q; break; }
            }
            if (rp != p) {
                for (int q = 0; q < 12; ++q) {
                    GS[p][q] = 0.0;
                    GS[q][p] = 0.0;
                }
                GS[p][p] = 1.0;
                bS[p] = 0.0;
            }
        }
    }
    __syncthreads();

    for (int j = 0; j < 12; ++j) {
        if (lane == j) {
            double s = GS[j][j];
            for (int k = 0; k < j; ++k) {
                double l = GS[j][k];
                s -= l * l;
            }
            GS[j][j] = sqrt(fmax(s, 1e-30));
        }
        __syncthreads();
        if (lane > j && lane < 12) {
            double s = GS[lane][j];
            for (int k = 0; k < j; ++k) s -= GS[lane][k] * GS[j][k];
            GS[lane][j] = s / GS[j][j];
        }
        __syncthreads();
    }

    double s = (lane < 12) ? bS[lane] : 0.0;
    for (int k = 0; k < 12; ++k) {
        if (lane == k) yS[k] = s / GS[k][k];
        __syncthreads();
        double yk = yS[k];
        if (lane > k && lane < 12) s -= GS[lane][k] * yk;
    }
    double tacc = 0.0;
    for (int k = 11; k >= 0; --k) {
        if (lane == k) uS[k] = (yS[k] - tacc) / GS[k][k];
        __syncthreads();
        double uk = uS[k];
        if (lane < k) tacc += GS[k][lane] * uk;
    }
    __syncthreads();

    if (lane < 12) {
        double c = uS[rep] / (double)mcnt;
        coeff[(size_t)b * 12 + lane] = (float)c;
        cS[lane] = (float)c;
    }
    __syncthreads();

    float sx = 0.0f;
#pragma unroll
    for (int p = 0; p < 12; ++p) sx += aS[p][lane] * cS[p];
    xhat[(size_t)b * 64 + lane] = sx;
}

// ---------------------------------------------------------------------------

extern "C" void kernel_launch(void* const* d_in, const int* in_sizes, int n_in,
                              void* d_out, int out_size, void* d_ws, size_t ws_size,
                              hipStream_t stream) {
    const float* x        = (const float*)d_in[0];
    const float* enc_w1   = (const float*)d_in[1];
    const float* enc_b1   = (const float*)d_in[2];
    const float* res_w    = (const float*)d_in[3];
    const float* res_b    = (const float*)d_in[4];
    const float* res_g    = (const float*)d_in[5];
    const float* res_beta = (const float*)d_in[6];
    const float* enc_w2   = (const float*)d_in[7];
    const float* enc_b2   = (const float*)d_in[8];
    const float* emb      = (const float*)d_in[9];

    float* out = (float*)d_out;

    // workspace layout
    float* h  = (float*)d_ws;            // B*512 f32 (32MB), reused after enc2
    float* tz = h + (size_t)B_ * DENC_;  // B*768 f32 (48MB): t then z
    // VQ scratch overlapping h (dead after enc2):
    float* se    = h;                                        // 2048
    float* sz    = h + 2048;                                 // ROWS_
    int*   idxw  = (int*)(h + 2048 + (size_t)ROWS_);         // ROWS_
    int*   cnts  = (int*)(h + 2048 + 2 * (size_t)ROWS_);     // 2048
    float* lossacc = (float*)(cnts + NE_);                   // 1 (+pad)
    __bf16* Ehi  = (__bf16*)(h + 2048 + 2 * (size_t)ROWS_ + 2048 + 16);
    __bf16* Emid = Ehi + (size_t)NE_ * 64;
    __bf16* Elo  = Emid + (size_t)NE_ * 64;
    // pre-split weight planes (transposed [N][K]) after tz:
    __bf16* W1h = (__bf16*)(tz + (size_t)B_ * 768);   // 512*64 each
    __bf16* W1m = W1h + (size_t)DENC_ * IN_;
    __bf16* W1l = W1m + (size_t)DENC_ * IN_;
    __bf16* Wrh = W1l + (size_t)DENC_ * IN_;          // 512*512 each
    __bf16* Wrm = Wrh + (size_t)DENC_ * DENC_;
    __bf16* Wrl = Wrm + (size_t)DENC_ * DENC_;
    __bf16* W2h = Wrl + (size_t)DENC_ * DENC_;        // 768*512 each
    __bf16* W2m = W2h + (size_t)768 * DENC_;
    __bf16* W2l = W2m + (size_t)768 * DENC_;

    float* t = tz;
    float* z = tz;

    // fused weight pre-split (one launch; W planes don't overlap h -> safe here)
    k_wsplit_all<<<(WS_S3 + 255) / 256, 256, 0, stream>>>(enc_w1, res_w, enc_w2,
                                                          W1h, W1m, W1l,
                                                          Wrh, Wrm, Wrl,
                                                          W2h, W2m, W2l);

    // encoder (MFMA path, 256-row blocks, double-buffered, XCD-swizzled)
    k_gemm_mfma<<<dim3(DENC_ / 64, B_ / 256), 256, 0, stream>>>(x, W1h, W1m, W1l, enc_b1, h, DENC_, IN_);
    for (int r = 0; r < 2; ++r) {
        k_gemm_mfma<<<dim3(DENC_ / 64, B_ / 256), 256, 0, stream>>>(h, Wrh, Wrm, Wrl, res_b, t, DENC_, DENC_);
        k_lnrelu<<<B_ / 4, 256, 0, stream>>>(t, h, res_g, res_beta);
    }
    k_gemm_mfma<<<dim3(768 / 64, B_ / 256), 256, 0, stream>>>(h, W2h, W2m, W2l, enc_b2, z, 768, DENC_);

    // VQ (k_eprep AFTER enc2: its outputs overlap h, which is dead only now)
    k_eprep<<<NE_ / 4 + NE_ / 256, 256, 0, stream>>>(emb, Ehi, Emid, Elo, se, cnts, lossacc);
    k_rowsq<<<ROWS_ / 64, 256, 0, stream>>>(z, sz);
    k_distm<<<ROWS_ / 128, 256, 0, stream>>>(z, se, sz, Ehi, Emid, Elo,
                                             idxw, out + IDXF_OFF, lossacc, cnts);
    k_lossperp<<<1, 256, 0, stream>>>(lossacc, cnts, out);
    k_pinv<<<B_, 64, 0, stream>>>(x, emb, idxw, out + COEF_OFF, out + XHAT_OFF);
}